// Round 1
// baseline (247.648 us; speedup 1.0000x reference)
//
#include <hip/hip_runtime.h>
#include <hip/hip_bf16.h>
#include <stdint.h>

typedef unsigned short ushort_t;

#define BB 4
#define SS 4096
#define DD 2048
#define KKC 64      // K channels
#define HH 32
#define NT (BB*SS)  // 16384 tokens
#define NQKV 192

typedef float f32x4 __attribute__((ext_vector_type(4)));
typedef short s16x8 __attribute__((ext_vector_type(8)));

__device__ __forceinline__ ushort_t f2bf(float f) {
    union { float f; uint32_t u; } c; c.f = f;
    uint32_t u = c.u + 0x7fffu + ((c.u >> 16) & 1u);
    return (ushort_t)(u >> 16);
}

// D = A(16x32) * B(32x16) + D, bf16 inputs, f32 acc.
// A lane map: row = l&15, k = 8*(l>>4)+e (contiguous 8).
// B lane map: col = l&15, k = 8*(l>>4)+e.
// C/D lane map: col = l&15, row = 4*(l>>4)+reg.
__device__ __forceinline__ void mfma16(f32x4& d, s16x8 a, s16x8 b) {
    asm volatile("v_mfma_f32_16x16x32_bf16 %0, %1, %2, %0" : "+v"(d) : "v"(a), "v"(b));
}

// ---------------- weight pre-convert to fragment-linear bf16 ----------------
// W1 layout: [s=16][kk=4][f=12][lane=64][e=8]; col = f*16+(l&15); k = s*128+kk*32+8*(l>>4)+e
__global__ void k_pre1(const float* __restrict__ qkv_w, ushort_t* __restrict__ W1) {
    int idx = blockIdx.x * 256 + threadIdx.x;      // 393216 total
    int e = idx & 7; int rest = idx >> 3;
    int lane = rest & 63; rest >>= 6;
    int f = rest % 12; rest /= 12;
    int kk = rest & 3; int s = rest >> 2;
    int col = f * 16 + (lane & 15);
    int k = s * 128 + kk * 32 + 8 * (lane >> 4) + e;
    W1[idx] = f2bf(qkv_w[(size_t)col * DD + k]);
}

// W2 layout: [F=128][kk=2][lane=64][e=8]; col = F*16+(l&15); k = kk*32+8*(l>>4)+e
__global__ void k_pre2(const float* __restrict__ out_w, ushort_t* __restrict__ W2) {
    int idx = blockIdx.x * 256 + threadIdx.x;      // 131072 total
    int e = idx & 7; int rest = idx >> 3;
    int lane = rest & 63; rest >>= 6;
    int kk = rest & 1; int F = rest >> 1;
    int n = F * 16 + (lane & 15);
    int k = kk * 32 + 8 * (lane >> 4) + e;
    W2[idx] = f2bf(out_w[(size_t)n * KKC + k]);
}

// ---------------- LN + QKV GEMM + feature map + kv partials ----------------
__global__ __launch_bounds__(256) void k_qkv(
    const float* __restrict__ x, const float* __restrict__ nw, const float* __restrict__ nb,
    const float* __restrict__ qkv_b, const float* __restrict__ fm_w, const float* __restrict__ fm_b,
    const ushort_t* __restrict__ W1,
    float* __restrict__ qfeat,          // [NT][64]
    float* __restrict__ kvpart)         // [256 blocks][32 h][8 g][6]
{
    __shared__ __align__(16) union {
        ushort_t bstage[4 * 12 * 64 * 8];   // 49152 B
        float cep[64][NQKV];                // 49152 B
    } sm;
    __shared__ float stats[64][2];

    const int tid = threadIdx.x;
    const int wave = tid >> 6, lane = tid & 63;
    const int m0 = blockIdx.x * 64;

    // ---- LN stats: wave w handles local tokens [16w, 16w+16)
    for (int tt = 0; tt < 16; ++tt) {
        int tok = m0 + wave * 16 + tt;
        const float4* xr = (const float4*)(x + (size_t)tok * DD);
        float s1 = 0.f, s2 = 0.f;
        #pragma unroll
        for (int j = 0; j < 8; ++j) {
            float4 v = xr[lane + 64 * j];
            s1 += v.x + v.y + v.z + v.w;
            s2 += v.x * v.x + v.y * v.y + v.z * v.z + v.w * v.w;
        }
        #pragma unroll
        for (int off = 32; off >= 1; off >>= 1) {
            s1 += __shfl_xor(s1, off);
            s2 += __shfl_xor(s2, off);
        }
        if (lane == 0) {
            float mu = s1 * (1.f / DD);
            float var = s2 * (1.f / DD) - mu * mu;
            stats[wave * 16 + tt][0] = mu;
            stats[wave * 16 + tt][1] = rsqrtf(var + 1e-5f);
        }
    }
    __syncthreads();

    f32x4 acc[12];
    #pragma unroll
    for (int f = 0; f < 12; ++f) acc[f] = (f32x4){0.f, 0.f, 0.f, 0.f};

    const int arow = wave * 16 + (lane & 15);
    const int tokA = m0 + arow;
    const float muA = stats[arow][0];
    const float rsA = stats[arow][1];
    const int ksub = 8 * (lane >> 4);

    for (int s = 0; s < 16; ++s) {         // BK = 128
        // stage B chunk (3072 x 16B entries, frag-linear) into LDS
        const uint4* src = (const uint4*)W1 + (size_t)s * 3072 + tid;
        uint4* dst = (uint4*)sm.bstage + tid;
        #pragma unroll
        for (int i = 0; i < 12; ++i) dst[i * 256] = src[i * 256];

        // A frags with on-the-fly LayerNorm -> bf16
        s16x8 afr[4];
        #pragma unroll
        for (int kk = 0; kk < 4; ++kk) {
            int k = s * 128 + kk * 32 + ksub;
            const float4* xp = (const float4*)(x + (size_t)tokA * DD + k);
            float4 v0 = xp[0], v1 = xp[1];
            const float4* wp = (const float4*)(nw + k);
            float4 w0 = wp[0], w1 = wp[1];
            const float4* bp = (const float4*)(nb + k);
            float4 b0 = bp[0], b1 = bp[1];
            union { ushort_t u[8]; s16x8 v; } cv;
            cv.u[0] = f2bf((v0.x - muA) * rsA * w0.x + b0.x);
            cv.u[1] = f2bf((v0.y - muA) * rsA * w0.y + b0.y);
            cv.u[2] = f2bf((v0.z - muA) * rsA * w0.z + b0.z);
            cv.u[3] = f2bf((v0.w - muA) * rsA * w0.w + b0.w);
            cv.u[4] = f2bf((v1.x - muA) * rsA * w1.x + b1.x);
            cv.u[5] = f2bf((v1.y - muA) * rsA * w1.y + b1.y);
            cv.u[6] = f2bf((v1.z - muA) * rsA * w1.z + b1.z);
            cv.u[7] = f2bf((v1.w - muA) * rsA * w1.w + b1.w);
            afr[kk] = cv.v;
        }
        __syncthreads();
        #pragma unroll
        for (int kk = 0; kk < 4; ++kk) {
            #pragma unroll
            for (int f = 0; f < 12; ++f) {
                s16x8 b = ((const s16x8*)sm.bstage)[(kk * 12 + f) * 64 + lane];
                mfma16(acc[f], afr[kk], b);
            }
        }
        __syncthreads();
    }

    // ---- epilogue: C -> LDS
    #pragma unroll
    for (int f = 0; f < 12; ++f) {
        int col = f * 16 + (lane & 15);
        int rbase = wave * 16 + (lane >> 4) * 4;
        #pragma unroll
        for (int r = 0; r < 4; ++r)
            sm.cep[rbase + r][col] = acc[f][r];
    }
    __syncthreads();

    // ---- per (token, head): bias + feature map + qfeat + kv partials
    const int h = tid & 31, g = tid >> 5;
    const float fm00 = fm_w[0], fm01 = fm_w[1], fm10 = fm_w[2], fm11 = fm_w[3];
    const float fb0 = fm_b[0], fb1 = fm_b[1];
    const float bq0 = qkv_b[2*h], bq1 = qkv_b[2*h+1];
    const float bk0 = qkv_b[64+2*h], bk1 = qkv_b[64+2*h+1];
    const float bv0 = qkv_b[128+2*h], bv1 = qkv_b[128+2*h+1];
    float kv00=0, kv01=0, kv10=0, kv11=0, ks0=0, ks1=0;
    for (int i = 0; i < 8; ++i) {
        int tt = g * 8 + i;
        float q0 = sm.cep[tt][2*h] + bq0,      q1 = sm.cep[tt][2*h+1] + bq1;
        float k0 = sm.cep[tt][64+2*h] + bk0,   k1 = sm.cep[tt][64+2*h+1] + bk1;
        float v0 = sm.cep[tt][128+2*h] + bv0,  v1 = sm.cep[tt][128+2*h+1] + bv1;
        float qp0 = fmaxf(fm00*q0 + fm01*q1 + fb0, 0.f);
        float qp1 = fmaxf(fm10*q0 + fm11*q1 + fb1, 0.f);
        float kp0 = fmaxf(fm00*k0 + fm01*k1 + fb0, 0.f);
        float kp1 = fmaxf(fm10*k0 + fm11*k1 + fb1, 0.f);
        size_t qo = (size_t)(m0 + tt) * KKC + 2*h;
        qfeat[qo] = qp0; qfeat[qo + 1] = qp1;
        kv00 += kp0*v0; kv01 += kp0*v1; kv10 += kp1*v0; kv11 += kp1*v1;
        ks0 += kp0; ks1 += kp1;
    }
    float* kp = kvpart + (((size_t)blockIdx.x * 32 + h) * 8 + g) * 6;
    kp[0]=kv00; kp[1]=kv01; kp[2]=kv10; kp[3]=kv11; kp[4]=ks0; kp[5]=ks1;
}

// ---------------- reduce kv partials (deterministic) ----------------
__global__ void k_red(const float* __restrict__ kvpart, float* __restrict__ kvstate) {
    int idx = blockIdx.x * 256 + threadIdx.x;   // 768 = B*H*6
    if (idx >= BB * HH * 6) return;
    int j = idx % 6, bh = idx / 6;
    int b = bh >> 5, h = bh & 31;
    float s = 0.f;
    for (int blk = 0; blk < 64; ++blk)
        #pragma unroll
        for (int g = 0; g < 8; ++g)
            s += kvpart[((((size_t)(b * 64 + blk)) * 32 + h) * 8 + g) * 6 + j];
    kvstate[idx] = s;
}

// ---------------- attn = q' kv / (q'.ksum + 1e-8), -> bf16 ----------------
__global__ __launch_bounds__(256) void k_attn(
    const float* __restrict__ qfeat, const float* __restrict__ kvstate,
    ushort_t* __restrict__ attnb) {
    int idx = blockIdx.x * 256 + threadIdx.x;   // NT*32
    int h = idx & 31, t = idx >> 5;
    int b = t >> 12;
    const float* kv = kvstate + (size_t)(b * 32 + h) * 6;
    float q0 = qfeat[(size_t)t * KKC + 2*h], q1 = qfeat[(size_t)t * KKC + 2*h + 1];
    float den = q0 * kv[4] + q1 * kv[5] + 1e-8f;
    float inv = 1.f / den;
    attnb[(size_t)t * KKC + 2*h]     = f2bf((q0 * kv[0] + q1 * kv[2]) * inv);
    attnb[(size_t)t * KKC + 2*h + 1] = f2bf((q0 * kv[1] + q1 * kv[3]) * inv);
}

// ---------------- out-projection GEMM + bias + residual ----------------
__global__ __launch_bounds__(256) void k_out(
    const ushort_t* __restrict__ attnb, const ushort_t* __restrict__ W2,
    const float* __restrict__ out_b, const float* __restrict__ x,
    float* __restrict__ out) {
    const int tid = threadIdx.x, wave = tid >> 6, lane = tid & 63;
    const int m0 = (blockIdx.x >> 3) * 64;
    const int n0 = (blockIdx.x & 7) * 256;
    const int arow = m0 + wave * 16 + (lane & 15);
    const int ksub = 8 * (lane >> 4);

    s16x8 a0 = *(const s16x8*)(attnb + (size_t)arow * KKC + ksub);
    s16x8 a1 = *(const s16x8*)(attnb + (size_t)arow * KKC + 32 + ksub);

    f32x4 acc[16];
    #pragma unroll
    for (int f = 0; f < 16; ++f) acc[f] = (f32x4){0.f, 0.f, 0.f, 0.f};
    #pragma unroll
    for (int f = 0; f < 16; ++f) {
        int F = (n0 >> 4) + f;
        s16x8 b0 = *(const s16x8*)(W2 + ((size_t)(F * 2 + 0) * 64 + lane) * 8);
        s16x8 b1 = *(const s16x8*)(W2 + ((size_t)(F * 2 + 1) * 64 + lane) * 8);
        mfma16(acc[f], a0, b0);
        mfma16(acc[f], a1, b1);
    }
    #pragma unroll
    for (int f = 0; f < 16; ++f) {
        int col = n0 + f * 16 + (lane & 15);
        int rbase = m0 + wave * 16 + (lane >> 4) * 4;
        float ob = out_b[col];
        #pragma unroll
        for (int r = 0; r < 4; ++r) {
            size_t off = (size_t)(rbase + r) * DD + col;
            out[off] = acc[f][r] + ob + x[off];
        }
    }
}

extern "C" void kernel_launch(void* const* d_in, const int* in_sizes, int n_in,
                              void* d_out, int out_size, void* d_ws, size_t ws_size,
                              hipStream_t stream) {
    const float* x     = (const float*)d_in[0];
    const float* nw    = (const float*)d_in[1];
    const float* nb    = (const float*)d_in[2];
    const float* qkv_w = (const float*)d_in[3];
    const float* qkv_b = (const float*)d_in[4];
    const float* fm_w  = (const float*)d_in[5];
    const float* fm_b  = (const float*)d_in[6];
    const float* out_w = (const float*)d_in[7];
    const float* out_b = (const float*)d_in[8];
    float* out = (float*)d_out;

    char* ws = (char*)d_ws;
    ushort_t* W1 = (ushort_t*)ws;     ws += (size_t)NQKV * DD * 2;     // 786432 B
    ushort_t* W2 = (ushort_t*)ws;     ws += (size_t)DD * KKC * 2;      // 262144 B
    float* qfeat = (float*)ws;        ws += (size_t)NT * KKC * 4;      // 4 MB
    ushort_t* attnb = (ushort_t*)ws;  ws += (size_t)NT * KKC * 2;      // 2 MB
    float* kvpart = (float*)ws;       ws += (size_t)256 * 32 * 8 * 6 * 4; // 1.5 MB
    float* kvstate = (float*)ws;      ws += (size_t)BB * HH * 6 * 4;
    // total ~8.9 MB of d_ws

    k_pre1<<<1536, 256, 0, stream>>>(qkv_w, W1);
    k_pre2<<<512, 256, 0, stream>>>(out_w, W2);
    k_qkv<<<NT / 64, 256, 0, stream>>>(x, nw, nb, qkv_b, fm_w, fm_b, W1, qfeat, kvpart);
    k_red<<<3, 256, 0, stream>>>(kvpart, kvstate);
    k_attn<<<NT * 32 / 256, 256, 0, stream>>>(qfeat, kvstate, attnb);
    k_out<<<(NT / 64) * 8, 256, 0, stream>>>(attnb, W2, out_b, x, out);
}

// Round 2
// 227.635 us; speedup vs baseline: 1.0879x; 1.0879x over previous
//
#include <hip/hip_runtime.h>
#include <hip/hip_bf16.h>
#include <stdint.h>

typedef unsigned short ushort_t;

#define BB 4
#define SS 4096
#define DD 2048
#define KKC 64      // K channels
#define HH 32
#define NT (BB*SS)  // 16384 tokens
#define NQKV 192

typedef float f32x4 __attribute__((ext_vector_type(4)));
typedef short s16x8 __attribute__((ext_vector_type(8)));

__device__ __forceinline__ ushort_t f2bf(float f) {
    union { float f; uint32_t u; } c; c.f = f;
    uint32_t u = c.u + 0x7fffu + ((c.u >> 16) & 1u);
    return (ushort_t)(u >> 16);
}

// D = A(16x32) * B(32x16) + D, bf16 inputs, f32 acc.
// A lane map: row = l&15, k = 8*(l>>4)+e. B: col = l&15, k = 8*(l>>4)+e.
// C/D: col = l&15, row = 4*(l>>4)+reg.
__device__ __forceinline__ void mfma16(f32x4& d, s16x8 a, s16x8 b) {
    asm volatile("v_mfma_f32_16x16x32_bf16 %0, %1, %2, %0" : "+v"(d) : "v"(a), "v"(b));
}

// async global->LDS, 16B per lane. lds dest must be wave-uniform base (HW adds lane*16).
__device__ __forceinline__ void gload_lds16(const void* gsrc, void* ldst) {
    __builtin_amdgcn_global_load_lds(
        (const __attribute__((address_space(1))) unsigned int*)gsrc,
        (__attribute__((address_space(3))) unsigned int*)ldst,
        16, 0, 0);
}

// ---------------- weight pre-convert to fragment-linear bf16 ----------------
// W1: [s=16][kk=4][f=12][lane=64][e=8]; col=f*16+(l&15); k=s*128+kk*32+8*(l>>4)+e
// W2: [F=128][kk=2][lane=64][e=8];      col=F*16+(l&15); k=kk*32+8*(l>>4)+e
__global__ void k_pre(const float* __restrict__ qkv_w, const float* __restrict__ out_w,
                      ushort_t* __restrict__ W1, ushort_t* __restrict__ W2) {
    int bid = blockIdx.x;
    if (bid < 1536) {
        int idx = bid * 256 + threadIdx.x;
        int e = idx & 7; int rest = idx >> 3;
        int lane = rest & 63; rest >>= 6;
        int f = rest % 12; rest /= 12;
        int kk = rest & 3; int s = rest >> 2;
        int col = f * 16 + (lane & 15);
        int k = s * 128 + kk * 32 + 8 * (lane >> 4) + e;
        W1[idx] = f2bf(qkv_w[(size_t)col * DD + k]);
    } else {
        int idx = (bid - 1536) * 256 + threadIdx.x;
        int e = idx & 7; int rest = idx >> 3;
        int lane = rest & 63; rest >>= 6;
        int kk = rest & 1; int F = rest >> 1;
        int n = F * 16 + (lane & 15);
        int k = kk * 32 + 8 * (lane >> 4) + e;
        W2[idx] = f2bf(out_w[(size_t)n * KKC + k]);
    }
}

// ---------------- LN + QKV GEMM + feature map + kv partials ----------------
// 512 threads = 8 waves: rowgrp = wave&1 (16 rows), fq = wave>>1 (3 of 12 N-frags).
// 32 tokens per block, 512 blocks.
__global__ __launch_bounds__(512, 4) void k_qkv(
    const float* __restrict__ x, const float* __restrict__ nw, const float* __restrict__ nb,
    const float* __restrict__ qkv_b, const float* __restrict__ fm_w, const float* __restrict__ fm_b,
    const ushort_t* __restrict__ W1,
    float* __restrict__ qfeat,          // [NT][64]
    float* __restrict__ kvpart)         // [512 blocks][32 h][6]
{
    __shared__ __align__(16) union {
        ushort_t bstage[4 * 12 * 64 * 8];   // 49152 B
        float cep[32][NQKV];                // 24576 B
    } sm;
    __shared__ float stats[32][2];
    __shared__ float kvred[32][16][6];

    const int tid = threadIdx.x;
    const int wave = tid >> 6, lane = tid & 63;
    const int m0 = blockIdx.x * 32;

    // ---- LN stats: wave w handles local tokens [4w, 4w+4)
    for (int tt = 0; tt < 4; ++tt) {
        int ltok = wave * 4 + tt;
        const float4* xr = (const float4*)(x + (size_t)(m0 + ltok) * DD);
        float s1 = 0.f, s2 = 0.f;
        #pragma unroll
        for (int j = 0; j < 8; ++j) {
            float4 v = xr[lane + 64 * j];
            s1 += v.x + v.y + v.z + v.w;
            s2 += v.x * v.x + v.y * v.y + v.z * v.z + v.w * v.w;
        }
        #pragma unroll
        for (int off = 32; off >= 1; off >>= 1) {
            s1 += __shfl_xor(s1, off);
            s2 += __shfl_xor(s2, off);
        }
        if (lane == 0) {
            float mu = s1 * (1.f / DD);
            float var = s2 * (1.f / DD) - mu * mu;
            stats[ltok][0] = mu;
            stats[ltok][1] = rsqrtf(var + 1e-5f);
        }
    }
    __syncthreads();

    f32x4 acc[3];
    #pragma unroll
    for (int j = 0; j < 3; ++j) acc[j] = (f32x4){0.f, 0.f, 0.f, 0.f};

    const int rowgrp = wave & 1, fq = wave >> 1;
    const int arow = rowgrp * 16 + (lane & 15);
    const int tokA = m0 + arow;
    const float muA = stats[arow][0];
    const float rsA = stats[arow][1];
    const int ksub = 8 * (lane >> 4);

    for (int s = 0; s < 16; ++s) {         // BK = 128
        // stage all 12 B-frag columns (48 KB) via async global->LDS, 16B/lane
        #pragma unroll
        for (int i = 0; i < 6; ++i) {
            int ebase = i * 512 + wave * 64;   // uint4 entry base for this wave
            gload_lds16((const char*)W1 + ((size_t)s * 3072 + ebase + lane) * 16,
                        (char*)sm.bstage + (size_t)ebase * 16);
        }

        // A frags with on-the-fly LayerNorm -> bf16
        s16x8 afr[4];
        #pragma unroll
        for (int kk = 0; kk < 4; ++kk) {
            int k = s * 128 + kk * 32 + ksub;
            const float4* xp = (const float4*)(x + (size_t)tokA * DD + k);
            float4 v0 = xp[0], v1 = xp[1];
            const float4* wp = (const float4*)(nw + k);
            float4 w0 = wp[0], w1 = wp[1];
            const float4* bp = (const float4*)(nb + k);
            float4 b0 = bp[0], b1 = bp[1];
            union { ushort_t u[8]; s16x8 v; } cv;
            cv.u[0] = f2bf((v0.x - muA) * rsA * w0.x + b0.x);
            cv.u[1] = f2bf((v0.y - muA) * rsA * w0.y + b0.y);
            cv.u[2] = f2bf((v0.z - muA) * rsA * w0.z + b0.z);
            cv.u[3] = f2bf((v0.w - muA) * rsA * w0.w + b0.w);
            cv.u[4] = f2bf((v1.x - muA) * rsA * w1.x + b1.x);
            cv.u[5] = f2bf((v1.y - muA) * rsA * w1.y + b1.y);
            cv.u[6] = f2bf((v1.z - muA) * rsA * w1.z + b1.z);
            cv.u[7] = f2bf((v1.w - muA) * rsA * w1.w + b1.w);
            afr[kk] = cv.v;
        }
        __syncthreads();
        #pragma unroll
        for (int kk = 0; kk < 4; ++kk) {
            #pragma unroll
            for (int j = 0; j < 3; ++j) {
                s16x8 b = ((const s16x8*)sm.bstage)[(kk * 12 + fq * 3 + j) * 64 + lane];
                mfma16(acc[j], afr[kk], b);
            }
        }
        __syncthreads();
    }

    // ---- epilogue: C -> LDS (each wave owns rows rowgrp*16..+15, cols fq*48..+47)
    #pragma unroll
    for (int j = 0; j < 3; ++j) {
        int col = (fq * 3 + j) * 16 + (lane & 15);
        int rbase = rowgrp * 16 + (lane >> 4) * 4;
        #pragma unroll
        for (int r = 0; r < 4; ++r)
            sm.cep[rbase + r][col] = acc[j][r];
    }
    __syncthreads();

    // ---- per (token, head): bias + feature map + qfeat + kv partials
    const int h = tid & 31, g = tid >> 5;      // g in 0..15, 2 tokens each
    const float fm00 = fm_w[0], fm01 = fm_w[1], fm10 = fm_w[2], fm11 = fm_w[3];
    const float fb0 = fm_b[0], fb1 = fm_b[1];
    const float bq0 = qkv_b[2*h], bq1 = qkv_b[2*h+1];
    const float bk0 = qkv_b[64+2*h], bk1 = qkv_b[64+2*h+1];
    const float bv0 = qkv_b[128+2*h], bv1 = qkv_b[128+2*h+1];
    float kv00=0, kv01=0, kv10=0, kv11=0, ks0=0, ks1=0;
    #pragma unroll
    for (int i = 0; i < 2; ++i) {
        int tt = g * 2 + i;
        float q0 = sm.cep[tt][2*h] + bq0,      q1 = sm.cep[tt][2*h+1] + bq1;
        float k0 = sm.cep[tt][64+2*h] + bk0,   k1 = sm.cep[tt][64+2*h+1] + bk1;
        float v0 = sm.cep[tt][128+2*h] + bv0,  v1 = sm.cep[tt][128+2*h+1] + bv1;
        float qp0 = fmaxf(fm00*q0 + fm01*q1 + fb0, 0.f);
        float qp1 = fmaxf(fm10*q0 + fm11*q1 + fb1, 0.f);
        float kp0 = fmaxf(fm00*k0 + fm01*k1 + fb0, 0.f);
        float kp1 = fmaxf(fm10*k0 + fm11*k1 + fb1, 0.f);
        size_t qo = (size_t)(m0 + tt) * KKC + 2*h;
        qfeat[qo] = qp0; qfeat[qo + 1] = qp1;
        kv00 += kp0*v0; kv01 += kp0*v1; kv10 += kp1*v0; kv11 += kp1*v1;
        ks0 += kp0; ks1 += kp1;
    }
    kvred[h][g][0]=kv00; kvred[h][g][1]=kv01; kvred[h][g][2]=kv10;
    kvred[h][g][3]=kv11; kvred[h][g][4]=ks0;  kvred[h][g][5]=ks1;
    __syncthreads();
    if (tid < 192) {
        int h2 = tid / 6, j = tid % 6;
        float s = 0.f;
        #pragma unroll
        for (int g2 = 0; g2 < 16; ++g2) s += kvred[h2][g2][j];
        kvpart[(size_t)blockIdx.x * 192 + tid] = s;
    }
}

// ---------------- reduce kv partials (deterministic) ----------------
__global__ void k_red(const float* __restrict__ kvpart, float* __restrict__ kvstate) {
    int idx = blockIdx.x * 256 + threadIdx.x;   // 768 = B*H*6
    if (idx >= BB * HH * 6) return;
    int b = idx / 192, r = idx % 192;
    float s = 0.f;
    for (int blk = 0; blk < 128; ++blk)
        s += kvpart[(size_t)(b * 128 + blk) * 192 + r];
    kvstate[idx] = s;  // [b][h][6]
}

// ---------------- out-projection GEMM (attn computed inline) + residual ----
__global__ __launch_bounds__(256) void k_out(
    const float* __restrict__ qfeat, const float* __restrict__ kvstate,
    const ushort_t* __restrict__ W2, const float* __restrict__ out_b,
    const float* __restrict__ x, float* __restrict__ out) {
    __shared__ float skv[192];
    const int tid = threadIdx.x, wave = tid >> 6, lane = tid & 63;
    const int m0 = (blockIdx.x >> 3) * 64;
    const int n0 = (blockIdx.x & 7) * 256;
    const int b = m0 >> 12;
    if (tid < 192) skv[tid] = kvstate[b * 192 + tid];

    const int arow = m0 + wave * 16 + (lane & 15);
    const int ksub = 8 * (lane >> 4);
    // qfeat channels [ksub, ksub+8) and [32+ksub, 32+ksub+8)
    float4 qa0 = *(const float4*)(qfeat + (size_t)arow * KKC + ksub);
    float4 qa1 = *(const float4*)(qfeat + (size_t)arow * KKC + ksub + 4);
    float4 qb0 = *(const float4*)(qfeat + (size_t)arow * KKC + 32 + ksub);
    float4 qb1 = *(const float4*)(qfeat + (size_t)arow * KKC + 32 + ksub + 4);
    __syncthreads();

    union { ushort_t u[8]; s16x8 v; } ca, cb;
    {
        float qs[8] = {qa0.x,qa0.y,qa0.z,qa0.w,qa1.x,qa1.y,qa1.z,qa1.w};
        float rs[8] = {qb0.x,qb0.y,qb0.z,qb0.w,qb1.x,qb1.y,qb1.z,qb1.w};
        #pragma unroll
        for (int e = 0; e < 8; e += 2) {
            int h = (ksub + e) >> 1;
            const float* kv = skv + h * 6;
            float q0 = qs[e], q1 = qs[e+1];
            float inv = 1.f / (q0 * kv[4] + q1 * kv[5] + 1e-8f);
            ca.u[e]   = f2bf((q0 * kv[0] + q1 * kv[2]) * inv);
            ca.u[e+1] = f2bf((q0 * kv[1] + q1 * kv[3]) * inv);
            const float* kw = skv + (h + 16) * 6;
            float p0 = rs[e], p1 = rs[e+1];
            float iw = 1.f / (p0 * kw[4] + p1 * kw[5] + 1e-8f);
            cb.u[e]   = f2bf((p0 * kw[0] + p1 * kw[2]) * iw);
            cb.u[e+1] = f2bf((p0 * kw[1] + p1 * kw[3]) * iw);
        }
    }

    f32x4 acc[16];
    #pragma unroll
    for (int f = 0; f < 16; ++f) acc[f] = (f32x4){0.f, 0.f, 0.f, 0.f};
    #pragma unroll
    for (int f = 0; f < 16; ++f) {
        int F = (n0 >> 4) + f;
        s16x8 b0 = *(const s16x8*)(W2 + ((size_t)(F * 2 + 0) * 64 + lane) * 8);
        s16x8 b1 = *(const s16x8*)(W2 + ((size_t)(F * 2 + 1) * 64 + lane) * 8);
        mfma16(acc[f], ca.v, b0);
        mfma16(acc[f], cb.v, b1);
    }
    #pragma unroll
    for (int f = 0; f < 16; ++f) {
        int col = n0 + f * 16 + (lane & 15);
        int rbase = m0 + wave * 16 + (lane >> 4) * 4;
        float ob = out_b[col];
        #pragma unroll
        for (int r = 0; r < 4; ++r) {
            size_t off = (size_t)(rbase + r) * DD + col;
            out[off] = acc[f][r] + ob + x[off];
        }
    }
}

extern "C" void kernel_launch(void* const* d_in, const int* in_sizes, int n_in,
                              void* d_out, int out_size, void* d_ws, size_t ws_size,
                              hipStream_t stream) {
    const float* x     = (const float*)d_in[0];
    const float* nw    = (const float*)d_in[1];
    const float* nb    = (const float*)d_in[2];
    const float* qkv_w = (const float*)d_in[3];
    const float* qkv_b = (const float*)d_in[4];
    const float* fm_w  = (const float*)d_in[5];
    const float* fm_b  = (const float*)d_in[6];
    const float* out_w = (const float*)d_in[7];
    const float* out_b = (const float*)d_in[8];
    float* out = (float*)d_out;

    char* ws = (char*)d_ws;
    ushort_t* W1 = (ushort_t*)ws;     ws += (size_t)NQKV * DD * 2;        // 786432 B
    ushort_t* W2 = (ushort_t*)ws;     ws += (size_t)DD * KKC * 2;         // 262144 B
    float* qfeat = (float*)ws;        ws += (size_t)NT * KKC * 4;         // 4 MB
    float* kvpart = (float*)ws;       ws += (size_t)512 * 192 * 4;        // 393216 B
    float* kvstate = (float*)ws;      ws += (size_t)BB * HH * 6 * 4;

    k_pre<<<2048, 256, 0, stream>>>(qkv_w, out_w, W1, W2);
    k_qkv<<<NT / 32, 512, 0, stream>>>(x, nw, nb, qkv_b, fm_w, fm_b, W1, qfeat, kvpart);
    k_red<<<3, 256, 0, stream>>>(kvpart, kvstate);
    k_out<<<(NT / 64) * 8, 256, 0, stream>>>(qfeat, kvstate, W2, out_b, x, out);
}

// Round 3
// 225.041 us; speedup vs baseline: 1.1005x; 1.0115x over previous
//
#include <hip/hip_runtime.h>
#include <hip/hip_bf16.h>
#include <stdint.h>

typedef unsigned short ushort_t;

#define BB 4
#define SS 4096
#define DD 2048
#define KKC 64      // K channels
#define HH 32
#define NT (BB*SS)  // 16384 tokens
#define NQKV 192

typedef float f32x4 __attribute__((ext_vector_type(4)));
typedef short s16x8 __attribute__((ext_vector_type(8)));

__device__ __forceinline__ ushort_t f2bf(float f) {
    union { float f; uint32_t u; } c; c.f = f;
    uint32_t u = c.u + 0x7fffu + ((c.u >> 16) & 1u);
    return (ushort_t)(u >> 16);
}

// D = A(16x32) * B(32x16) + D, bf16 inputs, f32 acc.
// A lane map: row = l&15, k = 8*(l>>4)+e. B: col = l&15, k = 8*(l>>4)+e.
// C/D: col = l&15, row = 4*(l>>4)+reg.
__device__ __forceinline__ void mfma16(f32x4& d, s16x8 a, s16x8 b) {
    asm volatile("v_mfma_f32_16x16x32_bf16 %0, %1, %2, %0" : "+v"(d) : "v"(a), "v"(b));
}

// async global->LDS, 16B per lane; lds dest wave-uniform base (HW adds lane*16).
__device__ __forceinline__ void gload_lds16(const void* gsrc, void* ldst) {
    __builtin_amdgcn_global_load_lds(
        (const __attribute__((address_space(1))) unsigned int*)gsrc,
        (__attribute__((address_space(3))) unsigned int*)ldst,
        16, 0, 0);
}

// ---------------- weight pre-convert to fragment-linear bf16 ----------------
// W1 entry E (16B): lane=E&63, f=(E>>6)%12, g=(E>>6)/12 (g=global kblk 0..63)
//   col=f*16+(lane&15); k0=g*32+8*(lane>>4); holds qkv_w[col][k0..k0+7]
// W2 entry E: lane=E&63, kk=(E>>6)&1, F=(E>>6)>>1
//   n=F*16+(lane&15); k0=kk*32+8*(lane>>4); holds out_w[n][k0..k0+7]
__global__ __launch_bounds__(256) void k_pre(
    const float* __restrict__ qkv_w, const float* __restrict__ out_w,
    ushort_t* __restrict__ W1, ushort_t* __restrict__ W2) {
    int E = blockIdx.x * 256 + threadIdx.x;
    if (E < 49152) {
        int lane = E & 63; int rest = E >> 6;
        int f = rest % 12, g = rest / 12;
        int col = f * 16 + (lane & 15);
        int k0 = g * 32 + 8 * (lane >> 4);
        const float* src = qkv_w + (size_t)col * DD + k0;
        union { ushort_t u[8]; uint4 v; } cv;
        #pragma unroll
        for (int e = 0; e < 8; ++e) cv.u[e] = f2bf(src[e]);
        *(uint4*)(W1 + (size_t)E * 8) = cv.v;
    } else {
        int E2 = E - 49152;   // 16384 entries
        int lane = E2 & 63; int rest = E2 >> 6;
        int kk = rest & 1, F = rest >> 1;
        int n = F * 16 + (lane & 15);
        int k0 = kk * 32 + 8 * (lane >> 4);
        const float* src = out_w + (size_t)n * KKC + k0;
        union { ushort_t u[8]; uint4 v; } cv;
        #pragma unroll
        for (int e = 0; e < 8; ++e) cv.u[e] = f2bf(src[e]);
        *(uint4*)(W2 + (size_t)E2 * 8) = cv.v;
    }
}

// ---------------- LayerNorm -> bf16 fragment-linear XN ----------------
// XN entry index = blk*4096 + g*64 + lane  (blk = token/16, g = kblk 0..63)
//   row = blk*16 + (lane&15); k0 = g*32 + 8*(lane>>4); holds xn[row][k0..k0+7]
__global__ __launch_bounds__(256) void k_ln(
    const float* __restrict__ x, const float* __restrict__ nw, const float* __restrict__ nb,
    ushort_t* __restrict__ XN) {
    __shared__ float stats[16][2];
    const int tid = threadIdx.x, wave = tid >> 6, lane = tid & 63;
    const int blk = blockIdx.x;           // 1024 blocks x 16 tokens

    for (int tt = 0; tt < 4; ++tt) {
        int tok = blk * 16 + wave * 4 + tt;
        const float4* xr = (const float4*)(x + (size_t)tok * DD);
        float s1 = 0.f, s2 = 0.f;
        #pragma unroll
        for (int j = 0; j < 8; ++j) {
            float4 v = xr[lane + 64 * j];
            s1 += v.x + v.y + v.z + v.w;
            s2 += v.x * v.x + v.y * v.y + v.z * v.z + v.w * v.w;
        }
        #pragma unroll
        for (int off = 32; off >= 1; off >>= 1) {
            s1 += __shfl_xor(s1, off);
            s2 += __shfl_xor(s2, off);
        }
        if (lane == 0) {
            float mu = s1 * (1.f / DD);
            float var = s2 * (1.f / DD) - mu * mu;
            stats[wave * 4 + tt][0] = mu;
            stats[wave * 4 + tt][1] = rsqrtf(var + 1e-5f);
        }
    }
    __syncthreads();

    #pragma unroll
    for (int it = 0; it < 16; ++it) {
        int i = it * 256 + tid;           // 4096 entries per block
        int g = i >> 6, l = i & 63;
        int row = l & 15;
        int tok = blk * 16 + row;
        int k0 = g * 32 + 8 * (l >> 4);
        const float4* xp = (const float4*)(x + (size_t)tok * DD + k0);
        float4 v0 = xp[0], v1 = xp[1];
        const float4* wp = (const float4*)(nw + k0);
        float4 w0 = wp[0], w1 = wp[1];
        const float4* bp = (const float4*)(nb + k0);
        float4 b0 = bp[0], b1 = bp[1];
        float mu = stats[row][0], rs = stats[row][1];
        union { ushort_t u[8]; uint4 v; } cv;
        cv.u[0] = f2bf((v0.x - mu) * rs * w0.x + b0.x);
        cv.u[1] = f2bf((v0.y - mu) * rs * w0.y + b0.y);
        cv.u[2] = f2bf((v0.z - mu) * rs * w0.z + b0.z);
        cv.u[3] = f2bf((v0.w - mu) * rs * w0.w + b0.w);
        cv.u[4] = f2bf((v1.x - mu) * rs * w1.x + b1.x);
        cv.u[5] = f2bf((v1.y - mu) * rs * w1.y + b1.y);
        cv.u[6] = f2bf((v1.z - mu) * rs * w1.z + b1.z);
        cv.u[7] = f2bf((v1.w - mu) * rs * w1.w + b1.w);
        *(uint4*)(XN + ((size_t)blk * 4096 + i) * 8) = cv.v;
    }
}

// ---------------- QKV GEMM (A=XN frag-linear) + feature map + kv partials ----
// 64 tokens/block, 256 blocks, 512 thr = 8 waves: rg = wave&3 (16 rows),
// ch = wave>>2 (96 cols = 6 frags). BK=64 (2 kblks), 32 steps, double-buffered B.
__global__ __launch_bounds__(512, 4) void k_qkv(
    const ushort_t* __restrict__ XN, const ushort_t* __restrict__ W1,
    const float* __restrict__ qkv_b, const float* __restrict__ fm_w, const float* __restrict__ fm_b,
    float* __restrict__ qfeat,          // [NT][64]
    float* __restrict__ kvpart)         // [256 blocks][192]
{
    __shared__ __align__(16) union {
        ushort_t bstage[2][1536 * 8];   // 2 x 24576 B
        float cep[64][NQKV];            // 49152 B
    } sm;
    __shared__ float kvred[32][16][6];

    const int tid = threadIdx.x;
    const int wave = tid >> 6, lane = tid & 63;
    const int rg = wave & 3, ch = wave >> 2;
    const int m0 = blockIdx.x * 64;
    const size_t abase = ((size_t)(blockIdx.x * 4 + rg) * 64) * 64 + lane; // entry idx, + g*64

    f32x4 acc[6];
    #pragma unroll
    for (int j = 0; j < 6; ++j) acc[j] = (f32x4){0.f, 0.f, 0.f, 0.f};

    // prologue: stage step 0, load A frags step 0
    #pragma unroll
    for (int i = 0; i < 3; ++i) {
        int ebase = i * 512 + wave * 64;
        gload_lds16((const char*)W1 + ((size_t)0 * 1536 + ebase + lane) * 16,
                    (char*)sm.bstage[0] + (size_t)ebase * 16);
    }
    s16x8 a0 = *(const s16x8*)(XN + (abase + 0 * 64) * 8);
    s16x8 a1 = *(const s16x8*)(XN + (abase + 1 * 64) * 8);
    __syncthreads();

    int cur = 0;
    for (int t = 0; t < 32; ++t) {
        s16x8 a0n, a1n;
        if (t < 31) {
            #pragma unroll
            for (int i = 0; i < 3; ++i) {
                int ebase = i * 512 + wave * 64;
                gload_lds16((const char*)W1 + ((size_t)(t + 1) * 1536 + ebase + lane) * 16,
                            (char*)sm.bstage[cur ^ 1] + (size_t)ebase * 16);
            }
            a0n = *(const s16x8*)(XN + (abase + (size_t)(2 * t + 2) * 64) * 8);
            a1n = *(const s16x8*)(XN + (abase + (size_t)(2 * t + 3) * 64) * 8);
        }
        #pragma unroll
        for (int j = 0; j < 6; ++j) {
            s16x8 b0 = ((const s16x8*)sm.bstage[cur])[(0 * 12 + ch * 6 + j) * 64 + lane];
            s16x8 b1 = ((const s16x8*)sm.bstage[cur])[(1 * 12 + ch * 6 + j) * 64 + lane];
            mfma16(acc[j], a0, b0);
            mfma16(acc[j], a1, b1);
        }
        __syncthreads();   // drains vmcnt (stage t+1, A t+1) + lgkm (reads of cur)
        a0 = a0n; a1 = a1n; cur ^= 1;
    }

    // ---- epilogue: C -> LDS (wave owns rows rg*16..+15, cols ch*96..+95)
    #pragma unroll
    for (int j = 0; j < 6; ++j) {
        int col = (ch * 6 + j) * 16 + (lane & 15);
        int rbase = rg * 16 + (lane >> 4) * 4;
        #pragma unroll
        for (int r = 0; r < 4; ++r)
            sm.cep[rbase + r][col] = acc[j][r];
    }
    __syncthreads();

    // ---- per (token, head): bias + feature map + qfeat + kv partials
    const int h = tid & 31, gg = tid >> 5;     // gg 0..15, 4 tokens each
    const float fm00 = fm_w[0], fm01 = fm_w[1], fm10 = fm_w[2], fm11 = fm_w[3];
    const float fb0 = fm_b[0], fb1 = fm_b[1];
    const float bq0 = qkv_b[2*h], bq1 = qkv_b[2*h+1];
    const float bk0 = qkv_b[64+2*h], bk1 = qkv_b[64+2*h+1];
    const float bv0 = qkv_b[128+2*h], bv1 = qkv_b[128+2*h+1];
    float kv00=0, kv01=0, kv10=0, kv11=0, ks0=0, ks1=0;
    #pragma unroll
    for (int i = 0; i < 4; ++i) {
        int tt = gg * 4 + i;
        float q0 = sm.cep[tt][2*h] + bq0,      q1 = sm.cep[tt][2*h+1] + bq1;
        float k0 = sm.cep[tt][64+2*h] + bk0,   k1 = sm.cep[tt][64+2*h+1] + bk1;
        float v0 = sm.cep[tt][128+2*h] + bv0,  v1 = sm.cep[tt][128+2*h+1] + bv1;
        float qp0 = fmaxf(fm00*q0 + fm01*q1 + fb0, 0.f);
        float qp1 = fmaxf(fm10*q0 + fm11*q1 + fb1, 0.f);
        float kp0 = fmaxf(fm00*k0 + fm01*k1 + fb0, 0.f);
        float kp1 = fmaxf(fm10*k0 + fm11*k1 + fb1, 0.f);
        *(float2*)(qfeat + (size_t)(m0 + tt) * KKC + 2*h) = make_float2(qp0, qp1);
        kv00 += kp0*v0; kv01 += kp0*v1; kv10 += kp1*v0; kv11 += kp1*v1;
        ks0 += kp0; ks1 += kp1;
    }
    kvred[h][gg][0]=kv00; kvred[h][gg][1]=kv01; kvred[h][gg][2]=kv10;
    kvred[h][gg][3]=kv11; kvred[h][gg][4]=ks0;  kvred[h][gg][5]=ks1;
    __syncthreads();
    if (tid < 192) {
        int h2 = tid / 6, j = tid % 6;
        float s = 0.f;
        #pragma unroll
        for (int g2 = 0; g2 < 16; ++g2) s += kvred[h2][g2][j];
        kvpart[(size_t)blockIdx.x * 192 + tid] = s;
    }
}

// ---------------- reduce kv partials (deterministic) ----------------
__global__ void k_red(const float* __restrict__ kvpart, float* __restrict__ kvstate) {
    int idx = blockIdx.x * 256 + threadIdx.x;   // 768 = B*H*6
    if (idx >= BB * HH * 6) return;
    int b = idx / 192, r = idx % 192;
    float s = 0.f;
    for (int blk = 0; blk < 64; ++blk)
        s += kvpart[(size_t)(b * 64 + blk) * 192 + r];
    kvstate[idx] = s;  // [b][h][6]
}

// ---------------- out-projection GEMM (attn computed inline) + residual ----
__global__ __launch_bounds__(256) void k_out(
    const float* __restrict__ qfeat, const float* __restrict__ kvstate,
    const ushort_t* __restrict__ W2, const float* __restrict__ out_b,
    const float* __restrict__ x, float* __restrict__ out) {
    __shared__ float skv[192];
    const int tid = threadIdx.x, wave = tid >> 6, lane = tid & 63;
    const int m0 = (blockIdx.x >> 3) * 64;
    const int n0 = (blockIdx.x & 7) * 256;
    const int b = m0 >> 12;
    if (tid < 192) skv[tid] = kvstate[b * 192 + tid];

    const int arow = m0 + wave * 16 + (lane & 15);
    const int ksub = 8 * (lane >> 4);
    float4 qa0 = *(const float4*)(qfeat + (size_t)arow * KKC + ksub);
    float4 qa1 = *(const float4*)(qfeat + (size_t)arow * KKC + ksub + 4);
    float4 qb0 = *(const float4*)(qfeat + (size_t)arow * KKC + 32 + ksub);
    float4 qb1 = *(const float4*)(qfeat + (size_t)arow * KKC + 32 + ksub + 4);
    __syncthreads();

    union { ushort_t u[8]; s16x8 v; } ca, cb;
    {
        float qs[8] = {qa0.x,qa0.y,qa0.z,qa0.w,qa1.x,qa1.y,qa1.z,qa1.w};
        float rs[8] = {qb0.x,qb0.y,qb0.z,qb0.w,qb1.x,qb1.y,qb1.z,qb1.w};
        #pragma unroll
        for (int e = 0; e < 8; e += 2) {
            int h = (ksub + e) >> 1;
            const float* kv = skv + h * 6;
            float q0 = qs[e], q1 = qs[e+1];
            float inv = 1.f / (q0 * kv[4] + q1 * kv[5] + 1e-8f);
            ca.u[e]   = f2bf((q0 * kv[0] + q1 * kv[2]) * inv);
            ca.u[e+1] = f2bf((q0 * kv[1] + q1 * kv[3]) * inv);
            const float* kw = skv + (h + 16) * 6;
            float p0 = rs[e], p1 = rs[e+1];
            float iw = 1.f / (p0 * kw[4] + p1 * kw[5] + 1e-8f);
            cb.u[e]   = f2bf((p0 * kw[0] + p1 * kw[2]) * iw);
            cb.u[e+1] = f2bf((p0 * kw[1] + p1 * kw[3]) * iw);
        }
    }

    f32x4 acc[16];
    #pragma unroll
    for (int f = 0; f < 16; ++f) acc[f] = (f32x4){0.f, 0.f, 0.f, 0.f};
    #pragma unroll
    for (int f = 0; f < 16; ++f) {
        int F = (n0 >> 4) + f;
        s16x8 b0 = *(const s16x8*)(W2 + ((size_t)(F * 2 + 0) * 64 + lane) * 8);
        s16x8 b1 = *(const s16x8*)(W2 + ((size_t)(F * 2 + 1) * 64 + lane) * 8);
        mfma16(acc[f], ca.v, b0);
        mfma16(acc[f], cb.v, b1);
    }
    #pragma unroll
    for (int f = 0; f < 16; ++f) {
        int col = n0 + f * 16 + (lane & 15);
        int rbase = m0 + wave * 16 + (lane >> 4) * 4;
        float ob = out_b[col];
        #pragma unroll
        for (int r = 0; r < 4; ++r) {
            size_t off = (size_t)(rbase + r) * DD + col;
            out[off] = acc[f][r] + ob + x[off];
        }
    }
}

extern "C" void kernel_launch(void* const* d_in, const int* in_sizes, int n_in,
                              void* d_out, int out_size, void* d_ws, size_t ws_size,
                              hipStream_t stream) {
    const float* x     = (const float*)d_in[0];
    const float* nw    = (const float*)d_in[1];
    const float* nb    = (const float*)d_in[2];
    const float* qkv_w = (const float*)d_in[3];
    const float* qkv_b = (const float*)d_in[4];
    const float* fm_w  = (const float*)d_in[5];
    const float* fm_b  = (const float*)d_in[6];
    const float* out_w = (const float*)d_in[7];
    const float* out_b = (const float*)d_in[8];
    float* out = (float*)d_out;

    char* ws = (char*)d_ws;
    ushort_t* W1 = (ushort_t*)ws;     ws += (size_t)NQKV * DD * 2;        // 786432 B
    ushort_t* W2 = (ushort_t*)ws;     ws += (size_t)DD * KKC * 2;         // 262144 B
    ushort_t* XN = (ushort_t*)ws;     ws += (size_t)NT * DD * 2;          // 64 MiB
    float* qfeat = (float*)ws;        ws += (size_t)NT * KKC * 4;         // 4 MiB
    float* kvpart = (float*)ws;       ws += (size_t)256 * 192 * 4;        // 196608 B
    float* kvstate = (float*)ws;      ws += (size_t)BB * HH * 6 * 4;

    k_pre<<<256, 256, 0, stream>>>(qkv_w, out_w, W1, W2);
    k_ln<<<NT / 16, 256, 0, stream>>>(x, nw, nb, XN);
    k_qkv<<<NT / 64, 512, 0, stream>>>(XN, W1, qkv_b, fm_w, fm_b, qfeat, kvpart);
    k_red<<<3, 256, 0, stream>>>(kvpart, kvstate);
    k_out<<<(NT / 64) * 8, 256, 0, stream>>>(qfeat, kvstate, W2, out_b, x, out);
}

// Round 4
// 164.003 us; speedup vs baseline: 1.5100x; 1.3722x over previous
//
#include <hip/hip_runtime.h>
#include <hip/hip_bf16.h>
#include <stdint.h>

typedef unsigned short ushort_t;

#define BB 4
#define SS 4096
#define DD 2048
#define KKC 64      // K channels
#define HH 32
#define NT (BB*SS)  // 16384 tokens
#define NQKV 192

typedef float f32x4 __attribute__((ext_vector_type(4)));
typedef short s16x8 __attribute__((ext_vector_type(8)));

__device__ __forceinline__ ushort_t f2bf(float f) {
    union { float f; uint32_t u; } c; c.f = f;
    uint32_t u = c.u + 0x7fffu + ((c.u >> 16) & 1u);
    return (ushort_t)(u >> 16);
}

// D = A(16x32) * B(32x16) + D, bf16 inputs, f32 acc.
// A lane map: row = l&15, k = 8*(l>>4)+e. B: col = l&15, k = 8*(l>>4)+e.
// C/D: col = l&15, row = 4*(l>>4)+reg.
__device__ __forceinline__ void mfma16(f32x4& d, s16x8 a, s16x8 b) {
    asm volatile("v_mfma_f32_16x16x32_bf16 %0, %1, %2, %0" : "+v"(d) : "v"(a), "v"(b));
}

// async global->LDS, 16B per lane; lds dest wave-uniform base (HW adds lane*16).
__device__ __forceinline__ void gload_lds16(const void* gsrc, void* ldst) {
    __builtin_amdgcn_global_load_lds(
        (const __attribute__((address_space(1))) unsigned int*)gsrc,
        (__attribute__((address_space(3))) unsigned int*)ldst,
        16, 0, 0);
}

// ---------------- weight pre-convert to fragment-linear bf16 ----------------
// W1 entry E (16B): lane=E&63, f=(E>>6)%12, g=(E>>6)/12 (g=global kblk 0..63)
//   col=f*16+(lane&15); k0=g*32+8*(lane>>4); holds qkv_w[col][k0..k0+7]
// W2 entry E: lane=E&63, kk=(E>>6)&1, F=(E>>6)>>1
//   n=F*16+(lane&15); k0=kk*32+8*(lane>>4); holds out_w[n][k0..k0+7]
__global__ __launch_bounds__(256) void k_pre(
    const float* __restrict__ qkv_w, const float* __restrict__ out_w,
    ushort_t* __restrict__ W1, ushort_t* __restrict__ W2) {
    int E = blockIdx.x * 256 + threadIdx.x;
    if (E < 49152) {
        int lane = E & 63; int rest = E >> 6;
        int f = rest % 12, g = rest / 12;
        int col = f * 16 + (lane & 15);
        int k0 = g * 32 + 8 * (lane >> 4);
        const float* src = qkv_w + (size_t)col * DD + k0;
        union { ushort_t u[8]; uint4 v; } cv;
        #pragma unroll
        for (int e = 0; e < 8; ++e) cv.u[e] = f2bf(src[e]);
        *(uint4*)(W1 + (size_t)E * 8) = cv.v;
    } else {
        int E2 = E - 49152;   // 16384 entries
        int lane = E2 & 63; int rest = E2 >> 6;
        int kk = rest & 1, F = rest >> 1;
        int n = F * 16 + (lane & 15);
        int k0 = kk * 32 + 8 * (lane >> 4);
        const float* src = out_w + (size_t)n * KKC + k0;
        union { ushort_t u[8]; uint4 v; } cv;
        #pragma unroll
        for (int e = 0; e < 8; ++e) cv.u[e] = f2bf(src[e]);
        *(uint4*)(W2 + (size_t)E2 * 8) = cv.v;
    }
}

// ---------------- LayerNorm -> bf16 fragment-linear XN ----------------
// XN entry index = blk*4096 + g*64 + lane  (blk = token/16, g = kblk 0..63)
//   row = blk*16 + (lane&15); k0 = g*32 + 8*(lane>>4); holds xn[row][k0..k0+7]
__global__ __launch_bounds__(256) void k_ln(
    const float* __restrict__ x, const float* __restrict__ nw, const float* __restrict__ nb,
    ushort_t* __restrict__ XN) {
    __shared__ float stats[16][2];
    const int tid = threadIdx.x, wave = tid >> 6, lane = tid & 63;
    const int blk = blockIdx.x;           // 1024 blocks x 16 tokens

    for (int tt = 0; tt < 4; ++tt) {
        int tok = blk * 16 + wave * 4 + tt;
        const float4* xr = (const float4*)(x + (size_t)tok * DD);
        float s1 = 0.f, s2 = 0.f;
        #pragma unroll
        for (int j = 0; j < 8; ++j) {
            float4 v = xr[lane + 64 * j];
            s1 += v.x + v.y + v.z + v.w;
            s2 += v.x * v.x + v.y * v.y + v.z * v.z + v.w * v.w;
        }
        #pragma unroll
        for (int off = 32; off >= 1; off >>= 1) {
            s1 += __shfl_xor(s1, off);
            s2 += __shfl_xor(s2, off);
        }
        if (lane == 0) {
            float mu = s1 * (1.f / DD);
            float var = s2 * (1.f / DD) - mu * mu;
            stats[wave * 4 + tt][0] = mu;
            stats[wave * 4 + tt][1] = rsqrtf(var + 1e-5f);
        }
    }
    __syncthreads();

    #pragma unroll
    for (int it = 0; it < 16; ++it) {
        int i = it * 256 + tid;           // 4096 entries per block
        int g = i >> 6, l = i & 63;
        int row = l & 15;
        int tok = blk * 16 + row;
        int k0 = g * 32 + 8 * (l >> 4);
        const float4* xp = (const float4*)(x + (size_t)tok * DD + k0);
        float4 v0 = xp[0], v1 = xp[1];
        const float4* wp = (const float4*)(nw + k0);
        float4 w0 = wp[0], w1 = wp[1];
        const float4* bp = (const float4*)(nb + k0);
        float4 b0 = bp[0], b1 = bp[1];
        float mu = stats[row][0], rs = stats[row][1];
        union { ushort_t u[8]; uint4 v; } cv;
        cv.u[0] = f2bf((v0.x - mu) * rs * w0.x + b0.x);
        cv.u[1] = f2bf((v0.y - mu) * rs * w0.y + b0.y);
        cv.u[2] = f2bf((v0.z - mu) * rs * w0.z + b0.z);
        cv.u[3] = f2bf((v0.w - mu) * rs * w0.w + b0.w);
        cv.u[4] = f2bf((v1.x - mu) * rs * w1.x + b1.x);
        cv.u[5] = f2bf((v1.y - mu) * rs * w1.y + b1.y);
        cv.u[6] = f2bf((v1.z - mu) * rs * w1.z + b1.z);
        cv.u[7] = f2bf((v1.w - mu) * rs * w1.w + b1.w);
        *(uint4*)(XN + ((size_t)blk * 4096 + i) * 8) = cv.v;
    }
}

// ---------------- QKV GEMM (A=XN frag-linear) + feature map + kv partials ----
// 64 tokens/block, 256 blocks, 512 thr = 8 waves: rg = wave&3 (16 rows),
// ch = wave>>2 (96 cols = 6 frags). BK=64 (2 kblks), 32 steps, double-buffered B.
__global__ __launch_bounds__(512, 4) void k_qkv(
    const ushort_t* __restrict__ XN, const ushort_t* __restrict__ W1,
    const float* __restrict__ qkv_b, const float* __restrict__ fm_w, const float* __restrict__ fm_b,
    float* __restrict__ qfeat,          // [NT][64]
    float* __restrict__ kvpart)         // [256 blocks][192]
{
    __shared__ __align__(16) union {
        ushort_t bstage[2][1536 * 8];   // 2 x 24576 B
        float cep[64][NQKV];            // 49152 B
    } sm;
    __shared__ float kvred[32][16][6];

    const int tid = threadIdx.x;
    const int wave = tid >> 6, lane = tid & 63;
    const int rg = wave & 3, ch = wave >> 2;
    const int m0 = blockIdx.x * 64;
    const size_t abase = ((size_t)(blockIdx.x * 4 + rg) * 64) * 64 + lane; // entry idx, + g*64

    f32x4 acc[6];
    #pragma unroll
    for (int j = 0; j < 6; ++j) acc[j] = (f32x4){0.f, 0.f, 0.f, 0.f};

    // prologue: stage step 0, load A frags step 0
    #pragma unroll
    for (int i = 0; i < 3; ++i) {
        int ebase = i * 512 + wave * 64;
        gload_lds16((const char*)W1 + ((size_t)0 * 1536 + ebase + lane) * 16,
                    (char*)sm.bstage[0] + (size_t)ebase * 16);
    }
    s16x8 a0 = *(const s16x8*)(XN + (abase + 0 * 64) * 8);
    s16x8 a1 = *(const s16x8*)(XN + (abase + 1 * 64) * 8);
    __syncthreads();

    int cur = 0;
    for (int t = 0; t < 32; ++t) {
        s16x8 a0n, a1n;
        if (t < 31) {
            #pragma unroll
            for (int i = 0; i < 3; ++i) {
                int ebase = i * 512 + wave * 64;
                gload_lds16((const char*)W1 + ((size_t)(t + 1) * 1536 + ebase + lane) * 16,
                            (char*)sm.bstage[cur ^ 1] + (size_t)ebase * 16);
            }
            a0n = *(const s16x8*)(XN + (abase + (size_t)(2 * t + 2) * 64) * 8);
            a1n = *(const s16x8*)(XN + (abase + (size_t)(2 * t + 3) * 64) * 8);
        }
        #pragma unroll
        for (int j = 0; j < 6; ++j) {
            s16x8 b0 = ((const s16x8*)sm.bstage[cur])[(0 * 12 + ch * 6 + j) * 64 + lane];
            s16x8 b1 = ((const s16x8*)sm.bstage[cur])[(1 * 12 + ch * 6 + j) * 64 + lane];
            mfma16(acc[j], a0, b0);
            mfma16(acc[j], a1, b1);
        }
        __syncthreads();   // drains vmcnt (stage t+1, A t+1) + lgkm (reads of cur)
        a0 = a0n; a1 = a1n; cur ^= 1;
    }

    // ---- epilogue: C -> LDS (wave owns rows rg*16..+15, cols ch*96..+95)
    #pragma unroll
    for (int j = 0; j < 6; ++j) {
        int col = (ch * 6 + j) * 16 + (lane & 15);
        int rbase = rg * 16 + (lane >> 4) * 4;
        #pragma unroll
        for (int r = 0; r < 4; ++r)
            sm.cep[rbase + r][col] = acc[j][r];
    }
    __syncthreads();

    // ---- per (token, head): bias + feature map + qfeat + kv partials
    const int h = tid & 31, gg = tid >> 5;     // gg 0..15, 4 tokens each
    const float fm00 = fm_w[0], fm01 = fm_w[1], fm10 = fm_w[2], fm11 = fm_w[3];
    const float fb0 = fm_b[0], fb1 = fm_b[1];
    const float bq0 = qkv_b[2*h], bq1 = qkv_b[2*h+1];
    const float bk0 = qkv_b[64+2*h], bk1 = qkv_b[64+2*h+1];
    const float bv0 = qkv_b[128+2*h], bv1 = qkv_b[128+2*h+1];
    float kv00=0, kv01=0, kv10=0, kv11=0, ks0=0, ks1=0;
    #pragma unroll
    for (int i = 0; i < 4; ++i) {
        int tt = gg * 4 + i;
        float q0 = sm.cep[tt][2*h] + bq0,      q1 = sm.cep[tt][2*h+1] + bq1;
        float k0 = sm.cep[tt][64+2*h] + bk0,   k1 = sm.cep[tt][64+2*h+1] + bk1;
        float v0 = sm.cep[tt][128+2*h] + bv0,  v1 = sm.cep[tt][128+2*h+1] + bv1;
        float qp0 = fmaxf(fm00*q0 + fm01*q1 + fb0, 0.f);
        float qp1 = fmaxf(fm10*q0 + fm11*q1 + fb1, 0.f);
        float kp0 = fmaxf(fm00*k0 + fm01*k1 + fb0, 0.f);
        float kp1 = fmaxf(fm10*k0 + fm11*k1 + fb1, 0.f);
        *(float2*)(qfeat + (size_t)(m0 + tt) * KKC + 2*h) = make_float2(qp0, qp1);
        kv00 += kp0*v0; kv01 += kp0*v1; kv10 += kp1*v0; kv11 += kp1*v1;
        ks0 += kp0; ks1 += kp1;
    }
    kvred[h][gg][0]=kv00; kvred[h][gg][1]=kv01; kvred[h][gg][2]=kv10;
    kvred[h][gg][3]=kv11; kvred[h][gg][4]=ks0;  kvred[h][gg][5]=ks1;
    __syncthreads();
    if (tid < 192) {
        int h2 = tid / 6, j = tid % 6;
        float s = 0.f;
        #pragma unroll
        for (int g2 = 0; g2 < 16; ++g2) s += kvred[h2][g2][j];
        kvpart[(size_t)blockIdx.x * 192 + tid] = s;
    }
}

// ---------------- reduce kv partials (deterministic) ----------------
__global__ void k_red(const float* __restrict__ kvpart, float* __restrict__ kvstate) {
    int idx = blockIdx.x * 256 + threadIdx.x;   // 768 = B*H*6
    if (idx >= BB * HH * 6) return;
    int b = idx / 192, r = idx % 192;
    float s = 0.f;
    for (int blk = 0; blk < 64; ++blk)
        s += kvpart[(size_t)(b * 64 + blk) * 192 + r];
    kvstate[idx] = s;  // [b][h][6]
}

// ---------------- out-projection GEMM (attn inline) + residual -------------
// Block: 32 tokens x 1024 cols; grid (NT/32)*2. 512 thr = 8 waves:
// rg = w&1 (rows rg*16..+15), cq = w>>1 (frags F = cq+4j, j=0..15).
// Epilogue: 4 chunks of 256 cols via LDS -> float4 global r/w.
#define CEP_STRIDE 260
__global__ __launch_bounds__(512, 4) void k_out(
    const float* __restrict__ qfeat, const float* __restrict__ kvstate,
    const ushort_t* __restrict__ W2, const float* __restrict__ out_b,
    const float* __restrict__ x, float* __restrict__ out) {
    __shared__ float skv[192];
    __shared__ __align__(16) float cep[32 * CEP_STRIDE];   // 33280 B
    const int tid = threadIdx.x, wave = tid >> 6, lane = tid & 63;
    const int rg = wave & 1, cq = wave >> 1;
    const int mb = blockIdx.x >> 1, nb = blockIdx.x & 1;
    const int m0 = mb * 32;
    const int n0 = nb * 1024;
    const int b = m0 >> 12;
    if (tid < 192) skv[tid] = kvstate[b * 192 + tid];

    const int arow = m0 + rg * 16 + (lane & 15);
    const int ksub = 8 * (lane >> 4);
    float4 qa0 = *(const float4*)(qfeat + (size_t)arow * KKC + ksub);
    float4 qa1 = *(const float4*)(qfeat + (size_t)arow * KKC + ksub + 4);
    float4 qb0 = *(const float4*)(qfeat + (size_t)arow * KKC + 32 + ksub);
    float4 qb1 = *(const float4*)(qfeat + (size_t)arow * KKC + 32 + ksub + 4);
    __syncthreads();

    // normalize q-features by (q . k_sum) inline -> bf16 A-fragments
    union { ushort_t u[8]; s16x8 v; } ca, cb;
    {
        float qs[8] = {qa0.x,qa0.y,qa0.z,qa0.w,qa1.x,qa1.y,qa1.z,qa1.w};
        float rs[8] = {qb0.x,qb0.y,qb0.z,qb0.w,qb1.x,qb1.y,qb1.z,qb1.w};
        #pragma unroll
        for (int e = 0; e < 8; e += 2) {
            int h = (ksub + e) >> 1;
            const float* kv = skv + h * 6;
            float q0 = qs[e], q1 = qs[e+1];
            float inv = 1.f / (q0 * kv[4] + q1 * kv[5] + 1e-8f);
            ca.u[e]   = f2bf((q0 * kv[0] + q1 * kv[2]) * inv);
            ca.u[e+1] = f2bf((q0 * kv[1] + q1 * kv[3]) * inv);
            const float* kw = skv + (h + 16) * 6;
            float p0 = rs[e], p1 = rs[e+1];
            float iw = 1.f / (p0 * kw[4] + p1 * kw[5] + 1e-8f);
            cb.u[e]   = f2bf((p0 * kw[0] + p1 * kw[2]) * iw);
            cb.u[e+1] = f2bf((p0 * kw[1] + p1 * kw[3]) * iw);
        }
    }

    f32x4 acc[16];
    #pragma unroll
    for (int j = 0; j < 16; ++j) acc[j] = (f32x4){0.f, 0.f, 0.f, 0.f};
    #pragma unroll
    for (int j = 0; j < 16; ++j) {
        int Fg = (n0 >> 4) + cq + 4 * j;
        s16x8 b0 = *(const s16x8*)(W2 + ((size_t)(Fg * 2 + 0) * 64 + lane) * 8);
        s16x8 b1 = *(const s16x8*)(W2 + ((size_t)(Fg * 2 + 1) * 64 + lane) * 8);
        mfma16(acc[j], ca.v, b0);
        mfma16(acc[j], cb.v, b1);
    }

    // epilogue: 4 chunks of 32 rows x 256 cols through LDS
    const int wrow = rg * 16 + 4 * (lane >> 4);
    #pragma unroll
    for (int n = 0; n < 4; ++n) {
        #pragma unroll
        for (int i = 0; i < 4; ++i) {
            int col = cq * 16 + i * 64 + (lane & 15);
            #pragma unroll
            for (int r = 0; r < 4; ++r)
                cep[(wrow + r) * CEP_STRIDE + col] = acc[4 * n + i][r];
        }
        __syncthreads();
        #pragma unroll
        for (int p = 0; p < 4; ++p) {
            int row = p * 8 + (tid >> 6);
            int c4 = tid & 63;
            float4 c = *(const float4*)(cep + row * CEP_STRIDE + c4 * 4);
            int gcol = n0 + n * 256 + c4 * 4;
            size_t off = (size_t)(m0 + row) * DD + gcol;
            float4 xr = *(const float4*)(x + off);
            float4 ob = *(const float4*)(out_b + gcol);
            float4 o;
            o.x = c.x + ob.x + xr.x; o.y = c.y + ob.y + xr.y;
            o.z = c.z + ob.z + xr.z; o.w = c.w + ob.w + xr.w;
            *(float4*)(out + off) = o;
        }
        __syncthreads();
    }
}

extern "C" void kernel_launch(void* const* d_in, const int* in_sizes, int n_in,
                              void* d_out, int out_size, void* d_ws, size_t ws_size,
                              hipStream_t stream) {
    const float* x     = (const float*)d_in[0];
    const float* nw    = (const float*)d_in[1];
    const float* nb    = (const float*)d_in[2];
    const float* qkv_w = (const float*)d_in[3];
    const float* qkv_b = (const float*)d_in[4];
    const float* fm_w  = (const float*)d_in[5];
    const float* fm_b  = (const float*)d_in[6];
    const float* out_w = (const float*)d_in[7];
    const float* out_b = (const float*)d_in[8];
    float* out = (float*)d_out;

    char* ws = (char*)d_ws;
    ushort_t* W1 = (ushort_t*)ws;     ws += (size_t)NQKV * DD * 2;        // 786432 B
    ushort_t* W2 = (ushort_t*)ws;     ws += (size_t)DD * KKC * 2;         // 262144 B
    ushort_t* XN = (ushort_t*)ws;     ws += (size_t)NT * DD * 2;          // 64 MiB
    float* qfeat = (float*)ws;        ws += (size_t)NT * KKC * 4;         // 4 MiB
    float* kvpart = (float*)ws;       ws += (size_t)256 * 192 * 4;        // 196608 B
    float* kvstate = (float*)ws;      ws += (size_t)BB * HH * 6 * 4;

    k_pre<<<256, 256, 0, stream>>>(qkv_w, out_w, W1, W2);
    k_ln<<<NT / 16, 256, 0, stream>>>(x, nw, nb, XN);
    k_qkv<<<NT / 64, 512, 0, stream>>>(XN, W1, qkv_b, fm_w, fm_b, qfeat, kvpart);
    k_red<<<3, 256, 0, stream>>>(kvpart, kvstate);
    k_out<<<(NT / 32) * 2, 512, 0, stream>>>(qfeat, kvstate, W2, out_b, x, out);
}

// Round 5
// 159.255 us; speedup vs baseline: 1.5550x; 1.0298x over previous
//
#include <hip/hip_runtime.h>
#include <hip/hip_bf16.h>
#include <stdint.h>

typedef unsigned short ushort_t;

#define BB 4
#define SS 4096
#define DD 2048
#define KKC 64      // K channels
#define HH 32
#define NT (BB*SS)  // 16384 tokens
#define NQKV 192

typedef float f32x4 __attribute__((ext_vector_type(4)));
typedef short s16x8 __attribute__((ext_vector_type(8)));

__device__ __forceinline__ ushort_t f2bf(float f) {
    union { float f; uint32_t u; } c; c.f = f;
    uint32_t u = c.u + 0x7fffu + ((c.u >> 16) & 1u);
    return (ushort_t)(u >> 16);
}

// D = A(16x32) * B(32x16) + D, bf16 inputs, f32 acc.
// A lane map: row = l&15, k = 8*(l>>4)+e. B: col = l&15, k = 8*(l>>4)+e.
// C/D: col = l&15, row = 4*(l>>4)+reg.
__device__ __forceinline__ void mfma16(f32x4& d, s16x8 a, s16x8 b) {
    asm volatile("v_mfma_f32_16x16x32_bf16 %0, %1, %2, %0" : "+v"(d) : "v"(a), "v"(b));
}

// async global->LDS, 16B per lane; lds dest wave-uniform base (HW adds lane*16).
__device__ __forceinline__ void gload_lds16(const void* gsrc, void* ldst) {
    __builtin_amdgcn_global_load_lds(
        (const __attribute__((address_space(1))) unsigned int*)gsrc,
        (__attribute__((address_space(3))) unsigned int*)ldst,
        16, 0, 0);
}

// ---------------- weight pre-convert to fragment-linear bf16 ----------------
// W1 entry E (16B): lane=E&63, f=(E>>6)%12, g=(E>>6)/12 (g=global kblk 0..63)
//   col=f*16+(lane&15); k0=g*32+8*(lane>>4); holds qkv_w[col][k0..k0+7]
// W2 entry E: lane=E&63, kk=(E>>6)&1, F=(E>>6)>>1
//   n=F*16+(lane&15); k0=kk*32+8*(lane>>4); holds out_w[n][k0..k0+7]
__global__ __launch_bounds__(256) void k_pre(
    const float* __restrict__ qkv_w, const float* __restrict__ out_w,
    ushort_t* __restrict__ W1, ushort_t* __restrict__ W2) {
    int E = blockIdx.x * 256 + threadIdx.x;
    if (E < 49152) {
        int lane = E & 63; int rest = E >> 6;
        int f = rest % 12, g = rest / 12;
        int col = f * 16 + (lane & 15);
        int k0 = g * 32 + 8 * (lane >> 4);
        const float* src = qkv_w + (size_t)col * DD + k0;
        union { ushort_t u[8]; uint4 v; } cv;
        #pragma unroll
        for (int e = 0; e < 8; ++e) cv.u[e] = f2bf(src[e]);
        *(uint4*)(W1 + (size_t)E * 8) = cv.v;
    } else {
        int E2 = E - 49152;   // 16384 entries
        int lane = E2 & 63; int rest = E2 >> 6;
        int kk = rest & 1, F = rest >> 1;
        int n = F * 16 + (lane & 15);
        int k0 = kk * 32 + 8 * (lane >> 4);
        const float* src = out_w + (size_t)n * KKC + k0;
        union { ushort_t u[8]; uint4 v; } cv;
        #pragma unroll
        for (int e = 0; e < 8; ++e) cv.u[e] = f2bf(src[e]);
        *(uint4*)(W2 + (size_t)E2 * 8) = cv.v;
    }
}

// ---------------- LayerNorm -> bf16 fragment-linear XN (LDS transpose) ------
// XN entry index = blk*4096 + g*64 + lane  (blk = token/16, g = kblk 0..63)
//   row = blk*16 + (lane&15); k0 = g*32 + 8*(lane>>4); holds xn[row][k0..k0+7]
#define XS_STRIDE 260
__global__ __launch_bounds__(256) void k_ln(
    const float* __restrict__ x, const float* __restrict__ nw, const float* __restrict__ nb,
    ushort_t* __restrict__ XN) {
    __shared__ float stats[16][2];
    __shared__ __align__(16) float xs[16 * XS_STRIDE];   // 16.6 KB
    const int tid = threadIdx.x, wave = tid >> 6, lane = tid & 63;
    const int blk = blockIdx.x;           // 1024 blocks x 16 tokens

    // ---- pass 1: stats (coalesced full-row stream; wave w -> tokens 4w..4w+3)
    for (int tt = 0; tt < 4; ++tt) {
        int tok = blk * 16 + wave * 4 + tt;
        const float4* xr = (const float4*)(x + (size_t)tok * DD);
        float s1 = 0.f, s2 = 0.f;
        #pragma unroll
        for (int j = 0; j < 8; ++j) {
            float4 v = xr[lane + 64 * j];
            s1 += v.x + v.y + v.z + v.w;
            s2 += v.x * v.x + v.y * v.y + v.z * v.z + v.w * v.w;
        }
        #pragma unroll
        for (int off = 32; off >= 1; off >>= 1) {
            s1 += __shfl_xor(s1, off);
            s2 += __shfl_xor(s2, off);
        }
        if (lane == 0) {
            float mu = s1 * (1.f / DD);
            float var = s2 * (1.f / DD) - mu * mu;
            stats[wave * 4 + tt][0] = mu;
            stats[wave * 4 + tt][1] = rsqrtf(var + 1e-5f);
        }
    }
    __syncthreads();

    // ---- pass 2: 8 chunks of 16 rows x 256 cols, transpose through LDS
    for (int kc = 0; kc < 8; ++kc) {
        // coalesced load: wave w, iter j -> row j*4+w, 1 KB contiguous
        #pragma unroll
        for (int j = 0; j < 4; ++j) {
            int row = j * 4 + wave;
            int tok = blk * 16 + row;
            float4 v = *(const float4*)(x + (size_t)tok * DD + kc * 256 + lane * 4);
            *(float4*)(xs + row * XS_STRIDE + lane * 4) = v;
        }
        __syncthreads();
        // emit 512 fragment entries (2 per thread), coalesced 16B writes
        #pragma unroll
        for (int q = 0; q < 2; ++q) {
            int ent = q * 256 + tid;        // 0..511
            int gl = ent >> 6;              // local kblk 0..7
            int l = ent & 63;
            int row = l & 15;
            int lc = gl * 32 + 8 * (l >> 4);
            int k0 = kc * 256 + lc;
            float4 v0 = *(const float4*)(xs + row * XS_STRIDE + lc);
            float4 v1 = *(const float4*)(xs + row * XS_STRIDE + lc + 4);
            const float4* wp = (const float4*)(nw + k0);
            float4 w0 = wp[0], w1 = wp[1];
            const float4* bp = (const float4*)(nb + k0);
            float4 b0 = bp[0], b1 = bp[1];
            float mu = stats[row][0], rs = stats[row][1];
            union { ushort_t u[8]; uint4 v; } cv;
            cv.u[0] = f2bf((v0.x - mu) * rs * w0.x + b0.x);
            cv.u[1] = f2bf((v0.y - mu) * rs * w0.y + b0.y);
            cv.u[2] = f2bf((v0.z - mu) * rs * w0.z + b0.z);
            cv.u[3] = f2bf((v0.w - mu) * rs * w0.w + b0.w);
            cv.u[4] = f2bf((v1.x - mu) * rs * w1.x + b1.x);
            cv.u[5] = f2bf((v1.y - mu) * rs * w1.y + b1.y);
            cv.u[6] = f2bf((v1.z - mu) * rs * w1.z + b1.z);
            cv.u[7] = f2bf((v1.w - mu) * rs * w1.w + b1.w);
            *(uint4*)(XN + ((size_t)blk * 4096 + (size_t)(kc * 8 + gl) * 64 + l) * 8) = cv.v;
        }
        __syncthreads();
    }
}

// ---------------- QKV GEMM (A=XN frag-linear) + feature map + kv partials ----
// 64 tokens/block, 256 blocks, 512 thr = 8 waves: rg = wave&3 (16 rows),
// ch = wave>>2 (96 cols = 6 frags). BK=64 (2 kblks), 32 steps, double-buffered B.
__global__ __launch_bounds__(512, 4) void k_qkv(
    const ushort_t* __restrict__ XN, const ushort_t* __restrict__ W1,
    const float* __restrict__ qkv_b, const float* __restrict__ fm_w, const float* __restrict__ fm_b,
    float* __restrict__ qfeat,          // [NT][64]
    float* __restrict__ kvpart)         // [256 blocks][192]
{
    __shared__ __align__(16) union {
        ushort_t bstage[2][1536 * 8];   // 2 x 24576 B
        float cep[64][NQKV];            // 49152 B
    } sm;
    __shared__ float kvred[32][16][6];

    const int tid = threadIdx.x;
    const int wave = tid >> 6, lane = tid & 63;
    const int rg = wave & 3, ch = wave >> 2;
    const int m0 = blockIdx.x * 64;
    const size_t abase = ((size_t)(blockIdx.x * 4 + rg) * 64) * 64 + lane; // entry idx, + g*64

    f32x4 acc[6];
    #pragma unroll
    for (int j = 0; j < 6; ++j) acc[j] = (f32x4){0.f, 0.f, 0.f, 0.f};

    // prologue: stage step 0, load A frags step 0
    #pragma unroll
    for (int i = 0; i < 3; ++i) {
        int ebase = i * 512 + wave * 64;
        gload_lds16((const char*)W1 + ((size_t)0 * 1536 + ebase + lane) * 16,
                    (char*)sm.bstage[0] + (size_t)ebase * 16);
    }
    s16x8 a0 = *(const s16x8*)(XN + (abase + 0 * 64) * 8);
    s16x8 a1 = *(const s16x8*)(XN + (abase + 1 * 64) * 8);
    __syncthreads();

    int cur = 0;
    for (int t = 0; t < 32; ++t) {
        s16x8 a0n, a1n;
        if (t < 31) {
            #pragma unroll
            for (int i = 0; i < 3; ++i) {
                int ebase = i * 512 + wave * 64;
                gload_lds16((const char*)W1 + ((size_t)(t + 1) * 1536 + ebase + lane) * 16,
                            (char*)sm.bstage[cur ^ 1] + (size_t)ebase * 16);
            }
            a0n = *(const s16x8*)(XN + (abase + (size_t)(2 * t + 2) * 64) * 8);
            a1n = *(const s16x8*)(XN + (abase + (size_t)(2 * t + 3) * 64) * 8);
        }
        #pragma unroll
        for (int j = 0; j < 6; ++j) {
            s16x8 b0 = ((const s16x8*)sm.bstage[cur])[(0 * 12 + ch * 6 + j) * 64 + lane];
            s16x8 b1 = ((const s16x8*)sm.bstage[cur])[(1 * 12 + ch * 6 + j) * 64 + lane];
            mfma16(acc[j], a0, b0);
            mfma16(acc[j], a1, b1);
        }
        __syncthreads();   // drains vmcnt (stage t+1, A t+1) + lgkm (reads of cur)
        a0 = a0n; a1 = a1n; cur ^= 1;
    }

    // ---- epilogue: C -> LDS (wave owns rows rg*16..+15, cols ch*96..+95)
    #pragma unroll
    for (int j = 0; j < 6; ++j) {
        int col = (ch * 6 + j) * 16 + (lane & 15);
        int rbase = rg * 16 + (lane >> 4) * 4;
        #pragma unroll
        for (int r = 0; r < 4; ++r)
            sm.cep[rbase + r][col] = acc[j][r];
    }
    __syncthreads();

    // ---- per (token, head): bias + feature map + qfeat + kv partials
    const int h = tid & 31, gg = tid >> 5;     // gg 0..15, 4 tokens each
    const float fm00 = fm_w[0], fm01 = fm_w[1], fm10 = fm_w[2], fm11 = fm_w[3];
    const float fb0 = fm_b[0], fb1 = fm_b[1];
    const float bq0 = qkv_b[2*h], bq1 = qkv_b[2*h+1];
    const float bk0 = qkv_b[64+2*h], bk1 = qkv_b[64+2*h+1];
    const float bv0 = qkv_b[128+2*h], bv1 = qkv_b[128+2*h+1];
    float kv00=0, kv01=0, kv10=0, kv11=0, ks0=0, ks1=0;
    #pragma unroll
    for (int i = 0; i < 4; ++i) {
        int tt = gg * 4 + i;
        float q0 = sm.cep[tt][2*h] + bq0,      q1 = sm.cep[tt][2*h+1] + bq1;
        float k0 = sm.cep[tt][64+2*h] + bk0,   k1 = sm.cep[tt][64+2*h+1] + bk1;
        float v0 = sm.cep[tt][128+2*h] + bv0,  v1 = sm.cep[tt][128+2*h+1] + bv1;
        float qp0 = fmaxf(fm00*q0 + fm01*q1 + fb0, 0.f);
        float qp1 = fmaxf(fm10*q0 + fm11*q1 + fb1, 0.f);
        float kp0 = fmaxf(fm00*k0 + fm01*k1 + fb0, 0.f);
        float kp1 = fmaxf(fm10*k0 + fm11*k1 + fb1, 0.f);
        *(float2*)(qfeat + (size_t)(m0 + tt) * KKC + 2*h) = make_float2(qp0, qp1);
        kv00 += kp0*v0; kv01 += kp0*v1; kv10 += kp1*v0; kv11 += kp1*v1;
        ks0 += kp0; ks1 += kp1;
    }
    kvred[h][gg][0]=kv00; kvred[h][gg][1]=kv01; kvred[h][gg][2]=kv10;
    kvred[h][gg][3]=kv11; kvred[h][gg][4]=ks0;  kvred[h][gg][5]=ks1;
    __syncthreads();
    if (tid < 192) {
        int h2 = tid / 6, j = tid % 6;
        float s = 0.f;
        #pragma unroll
        for (int g2 = 0; g2 < 16; ++g2) s += kvred[h2][g2][j];
        kvpart[(size_t)blockIdx.x * 192 + tid] = s;
    }
}

// ---------------- reduce kv partials (deterministic) ----------------
__global__ void k_red(const float* __restrict__ kvpart, float* __restrict__ kvstate) {
    int idx = blockIdx.x * 256 + threadIdx.x;   // 768 = B*H*6
    if (idx >= BB * HH * 6) return;
    int b = idx / 192, r = idx % 192;
    float s = 0.f;
    for (int blk = 0; blk < 64; ++blk)
        s += kvpart[(size_t)(b * 64 + blk) * 192 + r];
    kvstate[idx] = s;  // [b][h][6]
}

// ---------------- out-projection GEMM (attn inline) + residual -------------
// Block: 32 tokens x 1024 cols; grid (NT/32)*2. 512 thr = 8 waves:
// rg = w&1 (rows rg*16..+15), cq = w>>1 (frags F = cq+4j, j=0..15).
// Epilogue: 4 chunks of 256 cols via LDS -> float4 global r/w.
#define CEP_STRIDE 260
__global__ __launch_bounds__(512, 4) void k_out(
    const float* __restrict__ qfeat, const float* __restrict__ kvstate,
    const ushort_t* __restrict__ W2, const float* __restrict__ out_b,
    const float* __restrict__ x, float* __restrict__ out) {
    __shared__ float skv[192];
    __shared__ __align__(16) float cep[32 * CEP_STRIDE];   // 33280 B
    const int tid = threadIdx.x, wave = tid >> 6, lane = tid & 63;
    const int rg = wave & 1, cq = wave >> 1;
    const int mb = blockIdx.x >> 1, nb = blockIdx.x & 1;
    const int m0 = mb * 32;
    const int n0 = nb * 1024;
    const int b = m0 >> 12;
    if (tid < 192) skv[tid] = kvstate[b * 192 + tid];

    const int arow = m0 + rg * 16 + (lane & 15);
    const int ksub = 8 * (lane >> 4);
    float4 qa0 = *(const float4*)(qfeat + (size_t)arow * KKC + ksub);
    float4 qa1 = *(const float4*)(qfeat + (size_t)arow * KKC + ksub + 4);
    float4 qb0 = *(const float4*)(qfeat + (size_t)arow * KKC + 32 + ksub);
    float4 qb1 = *(const float4*)(qfeat + (size_t)arow * KKC + 32 + ksub + 4);
    __syncthreads();

    // normalize q-features by (q . k_sum) inline -> bf16 A-fragments
    union { ushort_t u[8]; s16x8 v; } ca, cb;
    {
        float qs[8] = {qa0.x,qa0.y,qa0.z,qa0.w,qa1.x,qa1.y,qa1.z,qa1.w};
        float rs[8] = {qb0.x,qb0.y,qb0.z,qb0.w,qb1.x,qb1.y,qb1.z,qb1.w};
        #pragma unroll
        for (int e = 0; e < 8; e += 2) {
            int h = (ksub + e) >> 1;
            const float* kv = skv + h * 6;
            float q0 = qs[e], q1 = qs[e+1];
            float inv = 1.f / (q0 * kv[4] + q1 * kv[5] + 1e-8f);
            ca.u[e]   = f2bf((q0 * kv[0] + q1 * kv[2]) * inv);
            ca.u[e+1] = f2bf((q0 * kv[1] + q1 * kv[3]) * inv);
            const float* kw = skv + (h + 16) * 6;
            float p0 = rs[e], p1 = rs[e+1];
            float iw = 1.f / (p0 * kw[4] + p1 * kw[5] + 1e-8f);
            cb.u[e]   = f2bf((p0 * kw[0] + p1 * kw[2]) * iw);
            cb.u[e+1] = f2bf((p0 * kw[1] + p1 * kw[3]) * iw);
        }
    }

    f32x4 acc[16];
    #pragma unroll
    for (int j = 0; j < 16; ++j) acc[j] = (f32x4){0.f, 0.f, 0.f, 0.f};
    #pragma unroll
    for (int j = 0; j < 16; ++j) {
        int Fg = (n0 >> 4) + cq + 4 * j;
        s16x8 b0 = *(const s16x8*)(W2 + ((size_t)(Fg * 2 + 0) * 64 + lane) * 8);
        s16x8 b1 = *(const s16x8*)(W2 + ((size_t)(Fg * 2 + 1) * 64 + lane) * 8);
        mfma16(acc[j], ca.v, b0);
        mfma16(acc[j], cb.v, b1);
    }

    // epilogue: 4 chunks of 32 rows x 256 cols through LDS
    const int wrow = rg * 16 + 4 * (lane >> 4);
    #pragma unroll
    for (int n = 0; n < 4; ++n) {
        #pragma unroll
        for (int i = 0; i < 4; ++i) {
            int col = cq * 16 + i * 64 + (lane & 15);
            #pragma unroll
            for (int r = 0; r < 4; ++r)
                cep[(wrow + r) * CEP_STRIDE + col] = acc[4 * n + i][r];
        }
        __syncthreads();
        #pragma unroll
        for (int p = 0; p < 4; ++p) {
            int row = p * 8 + (tid >> 6);
            int c4 = tid & 63;
            float4 c = *(const float4*)(cep + row * CEP_STRIDE + c4 * 4);
            int gcol = n0 + n * 256 + c4 * 4;
            size_t off = (size_t)(m0 + row) * DD + gcol;
            float4 xr = *(const float4*)(x + off);
            float4 ob = *(const float4*)(out_b + gcol);
            float4 o;
            o.x = c.x + ob.x + xr.x; o.y = c.y + ob.y + xr.y;
            o.z = c.z + ob.z + xr.z; o.w = c.w + ob.w + xr.w;
            *(float4*)(out + off) = o;
        }
        __syncthreads();
    }
}

extern "C" void kernel_launch(void* const* d_in, const int* in_sizes, int n_in,
                              void* d_out, int out_size, void* d_ws, size_t ws_size,
                              hipStream_t stream) {
    const float* x     = (const float*)d_in[0];
    const float* nw    = (const float*)d_in[1];
    const float* nb    = (const float*)d_in[2];
    const float* qkv_w = (const float*)d_in[3];
    const float* qkv_b = (const float*)d_in[4];
    const float* fm_w  = (const float*)d_in[5];
    const float* fm_b  = (const float*)d_in[6];
    const float* out_w = (const float*)d_in[7];
    const float* out_b = (const float*)d_in[8];
    float* out = (float*)d_out;

    char* ws = (char*)d_ws;
    ushort_t* W1 = (ushort_t*)ws;     ws += (size_t)NQKV * DD * 2;        // 786432 B
    ushort_t* W2 = (ushort_t*)ws;     ws += (size_t)DD * KKC * 2;         // 262144 B
    ushort_t* XN = (ushort_t*)ws;     ws += (size_t)NT * DD * 2;          // 64 MiB
    float* qfeat = (float*)ws;        ws += (size_t)NT * KKC * 4;         // 4 MiB
    float* kvpart = (float*)ws;       ws += (size_t)256 * 192 * 4;        // 196608 B
    float* kvstate = (float*)ws;      ws += (size_t)BB * HH * 6 * 4;

    k_pre<<<256, 256, 0, stream>>>(qkv_w, out_w, W1, W2);
    k_ln<<<NT / 16, 256, 0, stream>>>(x, nw, nb, XN);
    k_qkv<<<NT / 64, 512, 0, stream>>>(XN, W1, qkv_b, fm_w, fm_b, qfeat, kvpart);
    k_red<<<3, 256, 0, stream>>>(kvpart, kvstate);
    k_out<<<(NT / 32) * 2, 512, 0, stream>>>(qfeat, kvstate, W2, out_b, x, out);
}

// Round 6
// 151.743 us; speedup vs baseline: 1.6320x; 1.0495x over previous
//
#include <hip/hip_runtime.h>
#include <hip/hip_bf16.h>
#include <stdint.h>

typedef unsigned short ushort_t;

#define BB 4
#define SS 4096
#define DD 2048
#define KKC 64      // K channels
#define HH 32
#define NT (BB*SS)  // 16384 tokens
#define NQKV 192
#define QB 32       // tokens per k_qkv block

typedef float f32x4 __attribute__((ext_vector_type(4)));
typedef short s16x8 __attribute__((ext_vector_type(8)));

__device__ __forceinline__ ushort_t f2bf(float f) {
    union { float f; uint32_t u; } c; c.f = f;
    uint32_t u = c.u + 0x7fffu + ((c.u >> 16) & 1u);
    return (ushort_t)(u >> 16);
}

// packed f32 pair -> 2x bf16 (RNE), single HW instr
__device__ __forceinline__ uint32_t cvtpk(float lo, float hi) {
    uint32_t r;
    asm("v_cvt_pk_bf16_f32 %0, %1, %2" : "=v"(r) : "v"(lo), "v"(hi));
    return r;
}

// D = A(16x32) * B(32x16) + D, bf16 inputs, f32 acc.
// A lane map: row = l&15, k = 8*(l>>4)+e. B: col = l&15, k = 8*(l>>4)+e.
// C/D: col = l&15, row = 4*(l>>4)+reg.
__device__ __forceinline__ void mfma16(f32x4& d, s16x8 a, s16x8 b) {
    asm volatile("v_mfma_f32_16x16x32_bf16 %0, %1, %2, %0" : "+v"(d) : "v"(a), "v"(b));
}

// async global->LDS, 16B per lane; lds dest wave-uniform base (HW adds lane*16).
__device__ __forceinline__ void gload_lds16(const void* gsrc, void* ldst) {
    __builtin_amdgcn_global_load_lds(
        (const __attribute__((address_space(1))) unsigned int*)gsrc,
        (__attribute__((address_space(3))) unsigned int*)ldst,
        16, 0, 0);
}

// ---------------- weight pre-convert to fragment-linear bf16 ----------------
// W1 entry E (16B): lane=E&63, f=(E>>6)%12, g=(E>>6)/12 (g=global kblk 0..63)
//   col=f*16+(lane&15); k0=g*32+8*(lane>>4); holds qkv_w[col][k0..k0+7]
// W2 entry E: lane=E&63, kk=(E>>6)&1, F=(E>>6)>>1
//   n=F*16+(lane&15); k0=kk*32+8*(lane>>4); holds out_w[n][k0..k0+7]
__global__ __launch_bounds__(256) void k_pre(
    const float* __restrict__ qkv_w, const float* __restrict__ out_w,
    ushort_t* __restrict__ W1, ushort_t* __restrict__ W2) {
    int E = blockIdx.x * 256 + threadIdx.x;
    if (E < 49152) {
        int lane = E & 63; int rest = E >> 6;
        int f = rest % 12, g = rest / 12;
        int col = f * 16 + (lane & 15);
        int k0 = g * 32 + 8 * (lane >> 4);
        const float* src = qkv_w + (size_t)col * DD + k0;
        union { ushort_t u[8]; uint4 v; } cv;
        #pragma unroll
        for (int e = 0; e < 8; ++e) cv.u[e] = f2bf(src[e]);
        *(uint4*)(W1 + (size_t)E * 8) = cv.v;
    } else {
        int E2 = E - 49152;   // 16384 entries
        int lane = E2 & 63; int rest = E2 >> 6;
        int kk = rest & 1, F = rest >> 1;
        int n = F * 16 + (lane & 15);
        int k0 = kk * 32 + 8 * (lane >> 4);
        const float* src = out_w + (size_t)n * KKC + k0;
        union { ushort_t u[8]; uint4 v; } cv;
        #pragma unroll
        for (int e = 0; e < 8; ++e) cv.u[e] = f2bf(src[e]);
        *(uint4*)(W2 + (size_t)E2 * 8) = cv.v;
    }
}

// ------- fused LayerNorm + QKV GEMM + feature map + kv partials -------------
// 32 tokens/block, grid 512, 512 thr = 8 waves: rg = wave&1 (16 rows),
// ch = wave>>1 (3 N-frags each). BK=64, 32 steps, double-buffered B + x.
// x-chunk LDS is linear [32 rows][16 slots of 16B]; global source pre-swizzled
// slot^=(row&3)<<1, reads apply the same XOR (involution) -> ~2-way conflicts.
__global__ __launch_bounds__(512, 4) void k_qkv(
    const float* __restrict__ x, const float* __restrict__ nw, const float* __restrict__ nb,
    const ushort_t* __restrict__ W1, const float* __restrict__ qkv_b,
    const float* __restrict__ fm_w, const float* __restrict__ fm_b,
    float* __restrict__ qfeat,          // [NT][64]
    float* __restrict__ kvpart)         // [512 blocks][192]
{
    __shared__ __align__(16) union {
        struct {
            ushort_t b[2][1536 * 8];    // 2 x 24576 B
            float xs[2][QB * 64];       // 2 x 8192 B
        } st;
        float cep[QB][NQKV];            // 24576 B
    } sm;                                // 65536 B
    __shared__ float kvred[32][16][6];   // 12288 B
    __shared__ float stats[QB][2];

    const int tid = threadIdx.x;
    const int wave = tid >> 6, lane = tid & 63;
    const int rg = wave & 1, ch = wave >> 1;
    const int m0 = blockIdx.x * QB;

    // ---- stats pass: wave w -> tokens 4w..4w+3 (coalesced row stream)
    for (int tt = 0; tt < 4; ++tt) {
        int ltok = wave * 4 + tt;
        const float4* xr = (const float4*)(x + (size_t)(m0 + ltok) * DD);
        float s1 = 0.f, s2 = 0.f;
        #pragma unroll
        for (int j = 0; j < 8; ++j) {
            float4 v = xr[lane + 64 * j];
            s1 += v.x + v.y + v.z + v.w;
            s2 += v.x * v.x + v.y * v.y + v.z * v.z + v.w * v.w;
        }
        #pragma unroll
        for (int off = 32; off >= 1; off >>= 1) {
            s1 += __shfl_xor(s1, off);
            s2 += __shfl_xor(s2, off);
        }
        if (lane == 0) {
            float mu = s1 * (1.f / DD);
            float var = s2 * (1.f / DD) - mu * mu;
            stats[ltok][0] = mu;
            stats[ltok][1] = rsqrtf(var + 1e-5f);
        }
    }
    __syncthreads();

    const int rloc = rg * 16 + (lane & 15);     // A row (local)
    const int q4 = lane >> 4;                   // quarter-group
    const float muA = stats[rloc][0];
    const float rsA = stats[rloc][1];
    const int swz = (rloc & 3) << 1;            // 16B-slot XOR swizzle

    f32x4 acc[3];
    #pragma unroll
    for (int j = 0; j < 3; ++j) acc[j] = (f32x4){0.f, 0.f, 0.f, 0.f};

    // staging helpers ------------------------------------------------------
    const int xrow = (wave * 64 + lane) >> 4;           // row this lane stages
    const int xslot = ((wave * 64 + lane) & 15) ^ ((xrow & 3) << 1); // global slot
    const size_t xgbase = (size_t)(m0 + xrow) * DD + xslot * 4;

    // prologue: stage step 0 (B + x)
    #pragma unroll
    for (int i = 0; i < 3; ++i) {
        int ebase = i * 512 + wave * 64;
        gload_lds16((const char*)W1 + ((size_t)0 * 1536 + ebase + lane) * 16,
                    (char*)sm.st.b[0] + (size_t)ebase * 16);
    }
    gload_lds16(x + xgbase + 0 * 64, (char*)sm.st.xs[0] + (size_t)wave * 1024);
    __syncthreads();

    int cur = 0;
    for (int t = 0; t < 32; ++t) {
        if (t < 31) {
            #pragma unroll
            for (int i = 0; i < 3; ++i) {
                int ebase = i * 512 + wave * 64;
                gload_lds16((const char*)W1 + ((size_t)(t + 1) * 1536 + ebase + lane) * 16,
                            (char*)sm.st.b[cur ^ 1] + (size_t)ebase * 16);
            }
            gload_lds16(x + xgbase + (size_t)(t + 1) * 64,
                        (char*)sm.st.xs[cur ^ 1] + (size_t)wave * 1024);
        }
        // ---- A-frags: LDS x-chunk (swizzled read) + LN + packed bf16 cvt
        s16x8 afr[2];
        #pragma unroll
        for (int kb = 0; kb < 2; ++kb) {
            int sg = kb * 8 + 2 * q4;               // global 16B slot (even)
            int sl = sg ^ swz;                      // LDS slot
            const float* p = sm.st.xs[cur] + rloc * 64 + sl * 4;
            float4 v0 = ((const float4*)p)[0];
            float4 v1 = ((const float4*)p)[1];
            int k0 = t * 64 + kb * 32 + 8 * q4;
            float4 w0 = *(const float4*)(nw + k0);
            float4 w1 = *(const float4*)(nw + k0 + 4);
            float4 b0 = *(const float4*)(nb + k0);
            float4 b1 = *(const float4*)(nb + k0 + 4);
            float e0 = (v0.x - muA) * rsA * w0.x + b0.x;
            float e1 = (v0.y - muA) * rsA * w0.y + b0.y;
            float e2 = (v0.z - muA) * rsA * w0.z + b0.z;
            float e3 = (v0.w - muA) * rsA * w0.w + b0.w;
            float e4 = (v1.x - muA) * rsA * w1.x + b1.x;
            float e5 = (v1.y - muA) * rsA * w1.y + b1.y;
            float e6 = (v1.z - muA) * rsA * w1.z + b1.z;
            float e7 = (v1.w - muA) * rsA * w1.w + b1.w;
            union { uint32_t w[4]; s16x8 v; } cv;
            cv.w[0] = cvtpk(e0, e1);
            cv.w[1] = cvtpk(e2, e3);
            cv.w[2] = cvtpk(e4, e5);
            cv.w[3] = cvtpk(e6, e7);
            afr[kb] = cv.v;
        }
        // ---- B-frags + MFMA
        #pragma unroll
        for (int j = 0; j < 3; ++j) {
            s16x8 b0 = ((const s16x8*)sm.st.b[cur])[(0 * 12 + ch * 3 + j) * 64 + lane];
            s16x8 b1 = ((const s16x8*)sm.st.b[cur])[(1 * 12 + ch * 3 + j) * 64 + lane];
            mfma16(acc[j], afr[0], b0);
            mfma16(acc[j], afr[1], b1);
        }
        __syncthreads();   // staging t+1 complete; buf[cur] reads done
        cur ^= 1;
    }

    // ---- epilogue: C -> LDS (wave owns rows rg*16..+15, cols ch*48..+47)
    #pragma unroll
    for (int j = 0; j < 3; ++j) {
        int col = (ch * 3 + j) * 16 + (lane & 15);
        int rbase = rg * 16 + (lane >> 4) * 4;
        #pragma unroll
        for (int r = 0; r < 4; ++r)
            sm.cep[rbase + r][col] = acc[j][r];
    }
    __syncthreads();

    // ---- per (token, head): bias + feature map + qfeat + kv partials
    const int h = tid & 31, gg = tid >> 5;     // gg 0..15, 2 tokens each
    const float fm00 = fm_w[0], fm01 = fm_w[1], fm10 = fm_w[2], fm11 = fm_w[3];
    const float fb0 = fm_b[0], fb1 = fm_b[1];
    const float bq0 = qkv_b[2*h], bq1 = qkv_b[2*h+1];
    const float bk0 = qkv_b[64+2*h], bk1 = qkv_b[64+2*h+1];
    const float bv0 = qkv_b[128+2*h], bv1 = qkv_b[128+2*h+1];
    float kv00=0, kv01=0, kv10=0, kv11=0, ks0=0, ks1=0;
    #pragma unroll
    for (int i = 0; i < 2; ++i) {
        int tt = gg * 2 + i;
        float q0 = sm.cep[tt][2*h] + bq0,      q1 = sm.cep[tt][2*h+1] + bq1;
        float k0 = sm.cep[tt][64+2*h] + bk0,   k1 = sm.cep[tt][64+2*h+1] + bk1;
        float v0 = sm.cep[tt][128+2*h] + bv0,  v1 = sm.cep[tt][128+2*h+1] + bv1;
        float qp0 = fmaxf(fm00*q0 + fm01*q1 + fb0, 0.f);
        float qp1 = fmaxf(fm10*q0 + fm11*q1 + fb1, 0.f);
        float kp0 = fmaxf(fm00*k0 + fm01*k1 + fb0, 0.f);
        float kp1 = fmaxf(fm10*k0 + fm11*k1 + fb1, 0.f);
        *(float2*)(qfeat + (size_t)(m0 + tt) * KKC + 2*h) = make_float2(qp0, qp1);
        kv00 += kp0*v0; kv01 += kp0*v1; kv10 += kp1*v0; kv11 += kp1*v1;
        ks0 += kp0; ks1 += kp1;
    }
    kvred[h][gg][0]=kv00; kvred[h][gg][1]=kv01; kvred[h][gg][2]=kv10;
    kvred[h][gg][3]=kv11; kvred[h][gg][4]=ks0;  kvred[h][gg][5]=ks1;
    __syncthreads();
    if (tid < 192) {
        int h2 = tid / 6, j = tid % 6;
        float s = 0.f;
        #pragma unroll
        for (int g2 = 0; g2 < 16; ++g2) s += kvred[h2][g2][j];
        kvpart[(size_t)blockIdx.x * 192 + tid] = s;
    }
}

// ---------------- reduce kv partials (deterministic) ----------------
__global__ void k_red(const float* __restrict__ kvpart, float* __restrict__ kvstate) {
    int idx = blockIdx.x * 256 + threadIdx.x;   // 768 = B*H*6
    if (idx >= BB * HH * 6) return;
    int b = idx / 192, r = idx % 192;
    float s = 0.f;
    for (int blk = 0; blk < 128; ++blk)
        s += kvpart[(size_t)(b * 128 + blk) * 192 + r];
    kvstate[idx] = s;  // [b][h][6]
}

// ---------------- out-projection GEMM (attn inline) + residual -------------
// Block: 32 tokens x 1024 cols; grid (NT/32)*2. 512 thr = 8 waves:
// rg = w&1 (rows rg*16..+15), cq = w>>1 (frags F = cq+4j, j=0..15).
// Epilogue: 4 chunks of 256 cols via LDS -> float4 global r/w.
#define CEP_STRIDE 260
__global__ __launch_bounds__(512, 4) void k_out(
    const float* __restrict__ qfeat, const float* __restrict__ kvstate,
    const ushort_t* __restrict__ W2, const float* __restrict__ out_b,
    const float* __restrict__ x, float* __restrict__ out) {
    __shared__ float skv[192];
    __shared__ __align__(16) float cep[32 * CEP_STRIDE];   // 33280 B
    const int tid = threadIdx.x, wave = tid >> 6, lane = tid & 63;
    const int rg = wave & 1, cq = wave >> 1;
    const int mb = blockIdx.x >> 1, nb = blockIdx.x & 1;
    const int m0 = mb * 32;
    const int n0 = nb * 1024;
    const int b = m0 >> 12;
    if (tid < 192) skv[tid] = kvstate[b * 192 + tid];

    const int arow = m0 + rg * 16 + (lane & 15);
    const int ksub = 8 * (lane >> 4);
    float4 qa0 = *(const float4*)(qfeat + (size_t)arow * KKC + ksub);
    float4 qa1 = *(const float4*)(qfeat + (size_t)arow * KKC + ksub + 4);
    float4 qb0 = *(const float4*)(qfeat + (size_t)arow * KKC + 32 + ksub);
    float4 qb1 = *(const float4*)(qfeat + (size_t)arow * KKC + 32 + ksub + 4);
    __syncthreads();

    // normalize q-features by (q . k_sum) inline -> bf16 A-fragments
    union { ushort_t u[8]; s16x8 v; } ca, cb;
    {
        float qs[8] = {qa0.x,qa0.y,qa0.z,qa0.w,qa1.x,qa1.y,qa1.z,qa1.w};
        float rs[8] = {qb0.x,qb0.y,qb0.z,qb0.w,qb1.x,qb1.y,qb1.z,qb1.w};
        #pragma unroll
        for (int e = 0; e < 8; e += 2) {
            int h = (ksub + e) >> 1;
            const float* kv = skv + h * 6;
            float q0 = qs[e], q1 = qs[e+1];
            float inv = 1.f / (q0 * kv[4] + q1 * kv[5] + 1e-8f);
            ca.u[e]   = f2bf((q0 * kv[0] + q1 * kv[2]) * inv);
            ca.u[e+1] = f2bf((q0 * kv[1] + q1 * kv[3]) * inv);
            const float* kw = skv + (h + 16) * 6;
            float p0 = rs[e], p1 = rs[e+1];
            float iw = 1.f / (p0 * kw[4] + p1 * kw[5] + 1e-8f);
            cb.u[e]   = f2bf((p0 * kw[0] + p1 * kw[2]) * iw);
            cb.u[e+1] = f2bf((p0 * kw[1] + p1 * kw[3]) * iw);
        }
    }

    f32x4 acc[16];
    #pragma unroll
    for (int j = 0; j < 16; ++j) acc[j] = (f32x4){0.f, 0.f, 0.f, 0.f};
    #pragma unroll
    for (int j = 0; j < 16; ++j) {
        int Fg = (n0 >> 4) + cq + 4 * j;
        s16x8 b0 = *(const s16x8*)(W2 + ((size_t)(Fg * 2 + 0) * 64 + lane) * 8);
        s16x8 b1 = *(const s16x8*)(W2 + ((size_t)(Fg * 2 + 1) * 64 + lane) * 8);
        mfma16(acc[j], ca.v, b0);
        mfma16(acc[j], cb.v, b1);
    }

    // epilogue: 4 chunks of 32 rows x 256 cols through LDS
    const int wrow = rg * 16 + 4 * (lane >> 4);
    #pragma unroll
    for (int n = 0; n < 4; ++n) {
        #pragma unroll
        for (int i = 0; i < 4; ++i) {
            int col = cq * 16 + i * 64 + (lane & 15);
            #pragma unroll
            for (int r = 0; r < 4; ++r)
                cep[(wrow + r) * CEP_STRIDE + col] = acc[4 * n + i][r];
        }
        __syncthreads();
        #pragma unroll
        for (int p = 0; p < 4; ++p) {
            int row = p * 8 + (tid >> 6);
            int c4 = tid & 63;
            float4 c = *(const float4*)(cep + row * CEP_STRIDE + c4 * 4);
            int gcol = n0 + n * 256 + c4 * 4;
            size_t off = (size_t)(m0 + row) * DD + gcol;
            float4 xr = *(const float4*)(x + off);
            float4 ob = *(const float4*)(out_b + gcol);
            float4 o;
            o.x = c.x + ob.x + xr.x; o.y = c.y + ob.y + xr.y;
            o.z = c.z + ob.z + xr.z; o.w = c.w + ob.w + xr.w;
            *(float4*)(out + off) = o;
        }
        __syncthreads();
    }
}

extern "C" void kernel_launch(void* const* d_in, const int* in_sizes, int n_in,
                              void* d_out, int out_size, void* d_ws, size_t ws_size,
                              hipStream_t stream) {
    const float* x     = (const float*)d_in[0];
    const float* nw    = (const float*)d_in[1];
    const float* nb    = (const float*)d_in[2];
    const float* qkv_w = (const float*)d_in[3];
    const float* qkv_b = (const float*)d_in[4];
    const float* fm_w  = (const float*)d_in[5];
    const float* fm_b  = (const float*)d_in[6];
    const float* out_w = (const float*)d_in[7];
    const float* out_b = (const float*)d_in[8];
    float* out = (float*)d_out;

    char* ws = (char*)d_ws;
    ushort_t* W1 = (ushort_t*)ws;     ws += (size_t)NQKV * DD * 2;        // 786432 B
    ushort_t* W2 = (ushort_t*)ws;     ws += (size_t)DD * KKC * 2;         // 262144 B
    float* qfeat = (float*)ws;        ws += (size_t)NT * KKC * 4;         // 4 MiB
    float* kvpart = (float*)ws;       ws += (size_t)512 * 192 * 4;        // 393216 B
    float* kvstate = (float*)ws;      ws += (size_t)BB * HH * 6 * 4;

    k_pre<<<256, 256, 0, stream>>>(qkv_w, out_w, W1, W2);
    k_qkv<<<NT / QB, 512, 0, stream>>>(x, nw, nb, W1, qkv_b, fm_w, fm_b, qfeat, kvpart);
    k_red<<<3, 256, 0, stream>>>(kvpart, kvstate);
    k_out<<<(NT / 32) * 2, 512, 0, stream>>>(qfeat, kvstate, W2, out_b, x, out);
}

// Round 7
// 126.226 us; speedup vs baseline: 1.9619x; 1.2021x over previous
//
#include <hip/hip_runtime.h>
#include <hip/hip_bf16.h>
#include <stdint.h>

typedef unsigned short ushort_t;

#define BB 4
#define SS 4096
#define DD 2048
#define KKC 64      // K channels
#define HH 32
#define NT (BB*SS)  // 16384 tokens
#define NQKV 192
#define QB 32       // tokens per k_qkv block

typedef float f32x4 __attribute__((ext_vector_type(4)));
typedef short s16x8 __attribute__((ext_vector_type(8)));

__device__ __forceinline__ ushort_t f2bf(float f) {
    union { float f; uint32_t u; } c; c.f = f;
    uint32_t u = c.u + 0x7fffu + ((c.u >> 16) & 1u);
    return (ushort_t)(u >> 16);
}
__device__ __forceinline__ float bf2f(ushort_t b) {
    union { uint32_t u; float f; } c; c.u = (uint32_t)b << 16; return c.f;
}

// packed f32 pair -> 2x bf16 (RNE), single HW instr
__device__ __forceinline__ uint32_t cvtpk(float lo, float hi) {
    uint32_t r;
    asm("v_cvt_pk_bf16_f32 %0, %1, %2" : "=v"(r) : "v"(lo), "v"(hi));
    return r;
}

// D = A(16x32) * B(32x16) + D, bf16 inputs, f32 acc.
// A lane map: row = l&15, k = 8*(l>>4)+e. B: col = l&15, k = 8*(l>>4)+e.
// C/D: col = l&15, row = 4*(l>>4)+reg.
__device__ __forceinline__ void mfma16(f32x4& d, s16x8 a, s16x8 b) {
    asm volatile("v_mfma_f32_16x16x32_bf16 %0, %1, %2, %0" : "+v"(d) : "v"(a), "v"(b));
}

// async global->LDS, 16B per lane; lds dest wave-uniform base (HW adds lane*16).
__device__ __forceinline__ void gload_lds16(const void* gsrc, void* ldst) {
    __builtin_amdgcn_global_load_lds(
        (const __attribute__((address_space(1))) unsigned int*)gsrc,
        (__attribute__((address_space(3))) unsigned int*)ldst,
        16, 0, 0);
}

// ---------------- weight pre-convert to fragment-linear bf16 ----------------
// W1' entry E (16B): lane=E&63, f=(E>>6)%12, g=(E>>6)/12 (g=kblk 0..63)
//   col=f*16+(lane&15); k0=g*32+8*(lane>>4); holds qkv_w[col][k]*norm_w[k]
// W2 entry E: lane=E&63, kk=(E>>6)&1, F=(E>>6)>>1
//   n=F*16+(lane&15); k0=kk*32+8*(lane>>4); holds out_w[n][k0..k0+7]
__global__ __launch_bounds__(256) void k_pre(
    const float* __restrict__ qkv_w, const float* __restrict__ nw,
    const float* __restrict__ out_w,
    ushort_t* __restrict__ W1, ushort_t* __restrict__ W2) {
    int E = blockIdx.x * 256 + threadIdx.x;
    if (E < 49152) {
        int lane = E & 63; int rest = E >> 6;
        int f = rest % 12, g = rest / 12;
        int col = f * 16 + (lane & 15);
        int k0 = g * 32 + 8 * (lane >> 4);
        const float* src = qkv_w + (size_t)col * DD + k0;
        const float* wp = nw + k0;
        union { ushort_t u[8]; uint4 v; } cv;
        #pragma unroll
        for (int e = 0; e < 8; ++e) cv.u[e] = f2bf(src[e] * wp[e]);
        *(uint4*)(W1 + (size_t)E * 8) = cv.v;
    } else {
        int E2 = E - 49152;   // 16384 entries
        int lane = E2 & 63; int rest = E2 >> 6;
        int kk = rest & 1, F = rest >> 1;
        int n = F * 16 + (lane & 15);
        int k0 = kk * 32 + 8 * (lane >> 4);
        const float* src = out_w + (size_t)n * KKC + k0;
        union { ushort_t u[8]; uint4 v; } cv;
        #pragma unroll
        for (int e = 0; e < 8; ++e) cv.u[e] = f2bf(src[e]);
        *(uint4*)(W2 + (size_t)E2 * 8) = cv.v;
    }
}

// ------- per-col sums: S[col]=sum_k bf16(qkv_w*nw), qb2[col]=sum nb*qkv_w + qkv_b
__global__ __launch_bounds__(256) void k_colsum(
    const float* __restrict__ qkv_w, const float* __restrict__ nw,
    const float* __restrict__ nb, const float* __restrict__ qkv_b,
    float* __restrict__ S, float* __restrict__ qb2) {
    int col = blockIdx.x * 4 + (threadIdx.x >> 6);   // 48 blocks -> 192 cols
    int lane = threadIdx.x & 63;
    float s = 0.f, qb = 0.f;
    for (int j = 0; j < 32; ++j) {
        int k = j * 64 + lane;
        float w = qkv_w[(size_t)col * DD + k];
        s += bf2f(f2bf(w * nw[k]));
        qb += nb[k] * w;
    }
    #pragma unroll
    for (int off = 32; off >= 1; off >>= 1) {
        s += __shfl_xor(s, off);
        qb += __shfl_xor(qb, off);
    }
    if (lane == 0) { S[col] = s; qb2[col] = qb + qkv_b[col]; }
}

// ------- fused (LN-folded) QKV GEMM + stats + feature map + kv partials -----
// 32 tokens/block, grid 512, 512 thr = 8 waves: rg = wave&1 (16 rows),
// ch = wave>>1 (3 N-frags). BK=64, 32 steps, double-buffered B + x.
// A = raw x cast bf16; LN applied in epilogue via (rs, mu, S, qb2).
// x LDS [32 rows][16 x 16B slots], slot XOR-swizzled by (row&7) both sides.
__global__ __launch_bounds__(512, 4) void k_qkv(
    const float* __restrict__ x, const ushort_t* __restrict__ W1,
    const float* __restrict__ S, const float* __restrict__ qb2,
    const float* __restrict__ fm_w, const float* __restrict__ fm_b,
    float* __restrict__ qfeat,          // [NT][64]
    float* __restrict__ kvpart)         // [512 blocks][192]
{
    __shared__ __align__(16) union {
        struct {
            ushort_t b[2][1536 * 8];    // 2 x 24576 B
            float xs[2][QB * 64];       // 2 x 8192 B
        } st;
        float cep[QB][NQKV];            // 24576 B
    } sm;                                // 65536 B
    __shared__ float kvred[32][16][6];   // 12288 B
    __shared__ float stats4[4][32][2];   // 1024 B
    __shared__ float stats[QB][2];       // 256 B

    const int tid = threadIdx.x;
    const int wave = tid >> 6, lane = tid & 63;
    const int rg = wave & 1, ch = wave >> 1;
    const int m0 = blockIdx.x * QB;

    const int rloc = rg * 16 + (lane & 15);     // A row (local)
    const int q4 = lane >> 4;
    const int swz = rloc & 7;                   // 16B-slot XOR swizzle

    f32x4 acc[3];
    #pragma unroll
    for (int j = 0; j < 3; ++j) acc[j] = (f32x4){0.f, 0.f, 0.f, 0.f};
    float st1 = 0.f, st2 = 0.f;                 // stats partials

    // staging geometry
    const int lidx = wave * 64 + lane;          // 0..511 16B-entries
    const int xrow = lidx >> 4;
    const int xslot = (lidx & 15) ^ (xrow & 7); // global slot (swizzled source)
    const size_t xgbase = (size_t)(m0 + xrow) * DD + xslot * 4;

    // prologue: stage step 0
    #pragma unroll
    for (int i = 0; i < 3; ++i) {
        int ebase = i * 512 + wave * 64;
        gload_lds16((const char*)W1 + ((size_t)0 * 1536 + ebase + lane) * 16,
                    (char*)sm.st.b[0] + (size_t)ebase * 16);
    }
    gload_lds16(x + xgbase + 0 * 64, (char*)sm.st.xs[0] + (size_t)wave * 1024);

    for (int t = 0; t < 32; ++t) {
        const int cur = t & 1;
        __syncthreads();    // drains stage(t) (in flight since step t-1) + sync
        if (t < 31) {       // issue next stage immediately; full step to land
            #pragma unroll
            for (int i = 0; i < 3; ++i) {
                int ebase = i * 512 + wave * 64;
                gload_lds16((const char*)W1 + ((size_t)(t + 1) * 1536 + ebase + lane) * 16,
                            (char*)sm.st.b[cur ^ 1] + (size_t)ebase * 16);
            }
            gload_lds16(x + xgbase + (size_t)(t + 1) * 64,
                        (char*)sm.st.xs[cur ^ 1] + (size_t)wave * 1024);
        }
        // ---- A-frags: raw x from LDS (swizzled 16B reads) -> packed bf16
        s16x8 afr[2];
        const bool doStats = ((t & 3) == ch);
        #pragma unroll
        for (int kb = 0; kb < 2; ++kb) {
            int sg = kb * 8 + 2 * q4;
            const float* base = sm.st.xs[cur] + rloc * 64;
            float4 v0 = *(const float4*)(base + (sg ^ swz) * 4);
            float4 v1 = *(const float4*)(base + ((sg + 1) ^ swz) * 4);
            if (doStats) {
                st1 += v0.x + v0.y + v0.z + v0.w + v1.x + v1.y + v1.z + v1.w;
                st2 += v0.x*v0.x + v0.y*v0.y + v0.z*v0.z + v0.w*v0.w
                     + v1.x*v1.x + v1.y*v1.y + v1.z*v1.z + v1.w*v1.w;
            }
            union { uint32_t w[4]; s16x8 v; } cv;
            cv.w[0] = cvtpk(v0.x, v0.y);
            cv.w[1] = cvtpk(v0.z, v0.w);
            cv.w[2] = cvtpk(v1.x, v1.y);
            cv.w[3] = cvtpk(v1.z, v1.w);
            afr[kb] = cv.v;
        }
        // ---- B-frags + MFMA
        #pragma unroll
        for (int j = 0; j < 3; ++j) {
            s16x8 b0 = ((const s16x8*)sm.st.b[cur])[(0 * 12 + ch * 3 + j) * 64 + lane];
            s16x8 b1 = ((const s16x8*)sm.st.b[cur])[(1 * 12 + ch * 3 + j) * 64 + lane];
            mfma16(acc[j], afr[0], b0);
            mfma16(acc[j], afr[1], b1);
        }
    }

    // ---- stats: reduce over q4 lanes, publish per-ch partials
    st1 += __shfl_xor(st1, 16); st2 += __shfl_xor(st2, 16);
    st1 += __shfl_xor(st1, 32); st2 += __shfl_xor(st2, 32);
    if (lane < 16) { stats4[ch][rg * 16 + lane][0] = st1; stats4[ch][rg * 16 + lane][1] = st2; }
    __syncthreads();   // all st-region reads consumed; stats4 visible

    // ---- C -> LDS (clobbers staging union; safe now)
    #pragma unroll
    for (int j = 0; j < 3; ++j) {
        int col = (ch * 3 + j) * 16 + (lane & 15);
        int rbase = rg * 16 + (lane >> 4) * 4;
        #pragma unroll
        for (int r = 0; r < 4; ++r)
            sm.cep[rbase + r][col] = acc[j][r];
    }
    if (tid < 32) {
        float s1 = stats4[0][tid][0] + stats4[1][tid][0] + stats4[2][tid][0] + stats4[3][tid][0];
        float s2 = stats4[0][tid][1] + stats4[1][tid][1] + stats4[2][tid][1] + stats4[3][tid][1];
        float mu = s1 * (1.f / DD);
        float var = s2 * (1.f / DD) - mu * mu;
        stats[tid][0] = mu;
        stats[tid][1] = rsqrtf(var + 1e-5f);
    }
    __syncthreads();

    // ---- per (token, head): LN-affine + feature map + qfeat + kv partials
    const int h = tid & 31, gg = tid >> 5;     // gg 0..15, 2 tokens each
    const float fm00 = fm_w[0], fm01 = fm_w[1], fm10 = fm_w[2], fm11 = fm_w[3];
    const float fb0 = fm_b[0], fb1 = fm_b[1];
    const float Sq0 = S[2*h],      Sq1 = S[2*h+1],      cq0 = qb2[2*h],      cq1 = qb2[2*h+1];
    const float Sk0 = S[64+2*h],   Sk1 = S[64+2*h+1],   ck0 = qb2[64+2*h],   ck1 = qb2[64+2*h+1];
    const float Sv0 = S[128+2*h],  Sv1 = S[128+2*h+1],  cv0 = qb2[128+2*h],  cv1 = qb2[128+2*h+1];
    float kv00=0, kv01=0, kv10=0, kv11=0, ks0=0, ks1=0;
    #pragma unroll
    for (int i = 0; i < 2; ++i) {
        int tt = gg * 2 + i;
        float mu = stats[tt][0], rs = stats[tt][1];
        float f = mu * rs;
        float q0 = rs * sm.cep[tt][2*h]      - f * Sq0 + cq0;
        float q1 = rs * sm.cep[tt][2*h+1]    - f * Sq1 + cq1;
        float k0 = rs * sm.cep[tt][64+2*h]   - f * Sk0 + ck0;
        float k1 = rs * sm.cep[tt][64+2*h+1] - f * Sk1 + ck1;
        float v0 = rs * sm.cep[tt][128+2*h]  - f * Sv0 + cv0;
        float v1 = rs * sm.cep[tt][128+2*h+1]- f * Sv1 + cv1;
        float qp0 = fmaxf(fm00*q0 + fm01*q1 + fb0, 0.f);
        float qp1 = fmaxf(fm10*q0 + fm11*q1 + fb1, 0.f);
        float kp0 = fmaxf(fm00*k0 + fm01*k1 + fb0, 0.f);
        float kp1 = fmaxf(fm10*k0 + fm11*k1 + fb1, 0.f);
        *(float2*)(qfeat + (size_t)(m0 + tt) * KKC + 2*h) = make_float2(qp0, qp1);
        kv00 += kp0*v0; kv01 += kp0*v1; kv10 += kp1*v0; kv11 += kp1*v1;
        ks0 += kp0; ks1 += kp1;
    }
    kvred[h][gg][0]=kv00; kvred[h][gg][1]=kv01; kvred[h][gg][2]=kv10;
    kvred[h][gg][3]=kv11; kvred[h][gg][4]=ks0;  kvred[h][gg][5]=ks1;
    __syncthreads();
    if (tid < 192) {
        int h2 = tid / 6, j = tid % 6;
        float s = 0.f;
        #pragma unroll
        for (int g2 = 0; g2 < 16; ++g2) s += kvred[h2][g2][j];
        kvpart[(size_t)blockIdx.x * 192 + tid] = s;
    }
}

// ---------------- reduce kv partials (deterministic) ----------------
__global__ void k_red(const float* __restrict__ kvpart, float* __restrict__ kvstate) {
    int idx = blockIdx.x * 256 + threadIdx.x;   // 768 = B*H*6
    if (idx >= BB * HH * 6) return;
    int b = idx / 192, r = idx % 192;
    float s = 0.f;
    for (int blk = 0; blk < 128; ++blk)
        s += kvpart[(size_t)(b * 128 + blk) * 192 + r];
    kvstate[idx] = s;  // [b][h][6]
}

// ---------------- out-projection GEMM (attn inline) + residual -------------
// Block: 32 tokens x 1024 cols; grid (NT/32)*2. 512 thr = 8 waves:
// rg = w&1 (rows rg*16..+15), cq = w>>1 (frags F = cq+4j, j=0..15).
// Epilogue: 4 chunks of 256 cols via LDS -> float4 global r/w.
#define CEP_STRIDE 260
__global__ __launch_bounds__(512, 4) void k_out(
    const float* __restrict__ qfeat, const float* __restrict__ kvstate,
    const ushort_t* __restrict__ W2, const float* __restrict__ out_b,
    const float* __restrict__ x, float* __restrict__ out) {
    __shared__ float skv[192];
    __shared__ __align__(16) float cep[32 * CEP_STRIDE];   // 33280 B
    const int tid = threadIdx.x, wave = tid >> 6, lane = tid & 63;
    const int rg = wave & 1, cq = wave >> 1;
    const int mb = blockIdx.x >> 1, nb = blockIdx.x & 1;
    const int m0 = mb * 32;
    const int n0 = nb * 1024;
    const int b = m0 >> 12;
    if (tid < 192) skv[tid] = kvstate[b * 192 + tid];

    const int arow = m0 + rg * 16 + (lane & 15);
    const int ksub = 8 * (lane >> 4);
    float4 qa0 = *(const float4*)(qfeat + (size_t)arow * KKC + ksub);
    float4 qa1 = *(const float4*)(qfeat + (size_t)arow * KKC + ksub + 4);
    float4 qb0 = *(const float4*)(qfeat + (size_t)arow * KKC + 32 + ksub);
    float4 qb1 = *(const float4*)(qfeat + (size_t)arow * KKC + 32 + ksub + 4);
    __syncthreads();

    // normalize q-features by (q . k_sum) inline -> bf16 A-fragments
    union { ushort_t u[8]; s16x8 v; } ca, cb;
    {
        float qs[8] = {qa0.x,qa0.y,qa0.z,qa0.w,qa1.x,qa1.y,qa1.z,qa1.w};
        float rs[8] = {qb0.x,qb0.y,qb0.z,qb0.w,qb1.x,qb1.y,qb1.z,qb1.w};
        #pragma unroll
        for (int e = 0; e < 8; e += 2) {
            int h = (ksub + e) >> 1;
            const float* kv = skv + h * 6;
            float q0 = qs[e], q1 = qs[e+1];
            float inv = 1.f / (q0 * kv[4] + q1 * kv[5] + 1e-8f);
            ca.u[e]   = f2bf((q0 * kv[0] + q1 * kv[2]) * inv);
            ca.u[e+1] = f2bf((q0 * kv[1] + q1 * kv[3]) * inv);
            const float* kw = skv + (h + 16) * 6;
            float p0 = rs[e], p1 = rs[e+1];
            float iw = 1.f / (p0 * kw[4] + p1 * kw[5] + 1e-8f);
            cb.u[e]   = f2bf((p0 * kw[0] + p1 * kw[2]) * iw);
            cb.u[e+1] = f2bf((p0 * kw[1] + p1 * kw[3]) * iw);
        }
    }

    f32x4 acc[16];
    #pragma unroll
    for (int j = 0; j < 16; ++j) acc[j] = (f32x4){0.f, 0.f, 0.f, 0.f};
    #pragma unroll
    for (int j = 0; j < 16; ++j) {
        int Fg = (n0 >> 4) + cq + 4 * j;
        s16x8 b0 = *(const s16x8*)(W2 + ((size_t)(Fg * 2 + 0) * 64 + lane) * 8);
        s16x8 b1 = *(const s16x8*)(W2 + ((size_t)(Fg * 2 + 1) * 64 + lane) * 8);
        mfma16(acc[j], ca.v, b0);
        mfma16(acc[j], cb.v, b1);
    }

    // epilogue: 4 chunks of 32 rows x 256 cols through LDS
    const int wrow = rg * 16 + 4 * (lane >> 4);
    #pragma unroll
    for (int n = 0; n < 4; ++n) {
        #pragma unroll
        for (int i = 0; i < 4; ++i) {
            int col = cq * 16 + i * 64 + (lane & 15);
            #pragma unroll
            for (int r = 0; r < 4; ++r)
                cep[(wrow + r) * CEP_STRIDE + col] = acc[4 * n + i][r];
        }
        __syncthreads();
        #pragma unroll
        for (int p = 0; p < 4; ++p) {
            int row = p * 8 + (tid >> 6);
            int c4 = tid & 63;
            float4 c = *(const float4*)(cep + row * CEP_STRIDE + c4 * 4);
            int gcol = n0 + n * 256 + c4 * 4;
            size_t off = (size_t)(m0 + row) * DD + gcol;
            float4 xr = *(const float4*)(x + off);
            float4 ob = *(const float4*)(out_b + gcol);
            float4 o;
            o.x = c.x + ob.x + xr.x; o.y = c.y + ob.y + xr.y;
            o.z = c.z + ob.z + xr.z; o.w = c.w + ob.w + xr.w;
            *(float4*)(out + off) = o;
        }
        __syncthreads();
    }
}

extern "C" void kernel_launch(void* const* d_in, const int* in_sizes, int n_in,
                              void* d_out, int out_size, void* d_ws, size_t ws_size,
                              hipStream_t stream) {
    const float* x     = (const float*)d_in[0];
    const float* nw    = (const float*)d_in[1];
    const float* nb    = (const float*)d_in[2];
    const float* qkv_w = (const float*)d_in[3];
    const float* qkv_b = (const float*)d_in[4];
    const float* fm_w  = (const float*)d_in[5];
    const float* fm_b  = (const float*)d_in[6];
    const float* out_w = (const float*)d_in[7];
    const float* out_b = (const float*)d_in[8];
    float* out = (float*)d_out;

    char* ws = (char*)d_ws;
    ushort_t* W1 = (ushort_t*)ws;     ws += (size_t)NQKV * DD * 2;        // 786432 B
    ushort_t* W2 = (ushort_t*)ws;     ws += (size_t)DD * KKC * 2;         // 262144 B
    float* qfeat = (float*)ws;        ws += (size_t)NT * KKC * 4;         // 4 MiB
    float* kvpart = (float*)ws;       ws += (size_t)512 * 192 * 4;        // 393216 B
    float* kvstate = (float*)ws;      ws += (size_t)BB * HH * 6 * 4;      // 3072 B
    float* Svec = (float*)ws;         ws += (size_t)NQKV * 4;             // 768 B
    float* qb2 = (float*)ws;          ws += (size_t)NQKV * 4;             // 768 B

    k_pre<<<256, 256, 0, stream>>>(qkv_w, nw, out_w, W1, W2);
    k_colsum<<<48, 256, 0, stream>>>(qkv_w, nw, nb, qkv_b, Svec, qb2);
    k_qkv<<<NT / QB, 512, 0, stream>>>(x, W1, Svec, qb2, fm_w, fm_b, qfeat, kvpart);
    k_red<<<3, 256, 0, stream>>>(kvpart, kvstate);
    k_out<<<(NT / 32) * 2, 512, 0, stream>>>(qfeat, kvstate, W2, out_b, x, out);
}